// Round 1
// baseline (762.243 us; speedup 1.0000x reference)
//
#include <hip/hip_runtime.h>
#include <cstdint>
#include <cstddef>

typedef _Float16 f16;
typedef __attribute__((ext_vector_type(8))) _Float16 f16x8;
typedef __attribute__((ext_vector_type(4))) _Float16 f16x4;
typedef __attribute__((ext_vector_type(4))) float f32x4;

constexpr int kB  = 2;
constexpr int kS  = 2048;
constexpr int kD  = 2048;
constexpr int kH  = 16;
constexpr int kL  = 64;
constexpr int kHL = kH * kL;   // 1024
constexpr int kBS = kB * kS;   // 4096

__device__ __forceinline__ void load_lds16(const void* g, void* l) {
  __builtin_amdgcn_global_load_lds((const __attribute__((address_space(1))) void*)g,
                                   (__attribute__((address_space(3))) void*)l, 16, 0, 0);
}

__device__ __forceinline__ f32x4 mfma16(f16x8 a, f16x8 b, f32x4 c) {
  return __builtin_amdgcn_mfma_f32_16x16x32_f16(a, b, c, 0, 0, 0);
}

// ---------- fp32 -> fp16 cast, 4 elems/thread ----------
__global__ void cast_f32_f16(const float* __restrict__ in, f16* __restrict__ out, int n4) {
  int i = blockIdx.x * 256 + threadIdx.x;
  if (i >= n4) return;
  float4 f = ((const float4*)in)[i];
  f16x4 o; o[0] = (f16)f.x; o[1] = (f16)f.y; o[2] = (f16)f.z; o[3] = (f16)f.w;
  ((f16x4*)out)[i] = o;
}

// ---------- transpose-cast weight [2048][1024] -> [1024][2048] fp16 ----------
__global__ void transpose_w(const float* __restrict__ W, f16* __restrict__ Wt) {
  int idx = blockIdx.x * 256 + threadIdx.x;
  int k = idx & 2047, n = idx >> 11;
  Wt[(size_t)n * 2048 + k] = (f16)W[(size_t)k * 1024 + n];
}

// ---------- fold Wq[d][(h,c)] with Wkr[l][c] -> Wql_t[(h,l)][d] ----------
__global__ void fold_q(const float* __restrict__ Wq, const float* __restrict__ Wkr,
                       f16* __restrict__ Wqlt) {
  int idx = blockIdx.x * 256 + threadIdx.x;
  int d = idx & 2047, hl = idx >> 11;
  int h = hl >> 6, l = hl & 63;
  const float* wq = Wq + (size_t)d * 2048 + h * 128;
  const float* wk = Wkr + l * 128;
  float s = 0.f;
#pragma unroll 8
  for (int c = 0; c < 128; c++) s += wq[c] * wk[c];
  Wqlt[(size_t)hl * 2048 + d] = (f16)s;
}

__global__ void fold_bq(const float* __restrict__ bq, const float* __restrict__ Wkr,
                        float* __restrict__ bql) {
  int hl = blockIdx.x * 256 + threadIdx.x;
  if (hl >= kHL) return;
  int h = hl >> 6, l = hl & 63;
  float s = 0.f;
  for (int c = 0; c < 128; c++) s += bq[h * 128 + c] * Wkr[l * 128 + c];
  bql[hl] = s;
}

// ---------- fold Wvr[l][dv] with Wout[(h,dv)][d] -> W2_t[d][(h,l)] ----------
__global__ void fold_out(const float* __restrict__ Wvr, const float* __restrict__ Wout,
                         f16* __restrict__ W2t) {
  int idx = blockIdx.x * 256 + threadIdx.x;
  int hl = idx & 1023, d = idx >> 10;
  int h = hl >> 6, l = hl & 63;
  float s = 0.f;
#pragma unroll 8
  for (int c = 0; c < 128; c++) s += Wvr[l * 128 + c] * Wout[(size_t)(h * 128 + c) * 2048 + d];
  W2t[(size_t)d * 1024 + hl] = (f16)s;
}

// ---------- MFMA GEMM: C[M,N] = A[M,K] @ Bt[N,K]^T + bias ----------
// 128x128 tile, BK=64, 4 waves (2x2), global_load_lds staging.
template <typename OutT>
__device__ __forceinline__ void gemm_body(const f16* __restrict__ A, const f16* __restrict__ Bt,
                                          const float* __restrict__ bias, OutT* __restrict__ C,
                                          int N, int K) {
  __shared__ f16 sA[128 * 64];
  __shared__ f16 sB[128 * 64];
  const int tid = threadIdx.x;
  const int w = tid >> 6, lane = tid & 63;
  const int quad = lane >> 4, l16 = lane & 15;
  const int wm = w >> 1, wn = w & 1;
  const int m0 = blockIdx.y * 128, n0 = blockIdx.x * 128;
  const int rowA = lane >> 3, colA = (lane & 7) * 8;

  f32x4 acc[4][4];
  for (int i = 0; i < 4; i++)
    for (int j = 0; j < 4; j++) acc[i][j] = (f32x4){0.f, 0.f, 0.f, 0.f};

  for (int k0 = 0; k0 < K; k0 += 64) {
    __syncthreads();
#pragma unroll
    for (int c = 0; c < 4; c++) {
      int rl = w * 32 + c * 8;
      load_lds16(A + (size_t)(m0 + rl + rowA) * K + k0 + colA, &sA[rl * 64]);
      load_lds16(Bt + (size_t)(n0 + rl + rowA) * K + k0 + colA, &sB[rl * 64]);
    }
    __syncthreads();
#pragma unroll
    for (int ks = 0; ks < 2; ks++) {
      f16x8 af[4], bfr[4];
#pragma unroll
      for (int mt = 0; mt < 4; mt++)
        af[mt] = *(const f16x8*)&sA[(wm * 64 + mt * 16 + l16) * 64 + ks * 32 + quad * 8];
#pragma unroll
      for (int nt = 0; nt < 4; nt++)
        bfr[nt] = *(const f16x8*)&sB[(wn * 64 + nt * 16 + l16) * 64 + ks * 32 + quad * 8];
#pragma unroll
      for (int mt = 0; mt < 4; mt++) {
#pragma unroll
        for (int nt = 0; nt < 4; nt++)
          acc[mt][nt] = mfma16(af[mt], bfr[nt], acc[mt][nt]);
      }
    }
  }
#pragma unroll
  for (int mt = 0; mt < 4; mt++) {
#pragma unroll
    for (int nt = 0; nt < 4; nt++) {
      int col = n0 + wn * 64 + nt * 16 + l16;
      float bv = bias[col];
#pragma unroll
      for (int r = 0; r < 4; r++) {
        int row = m0 + wm * 64 + mt * 16 + quad * 4 + r;
        C[(size_t)row * N + col] = (OutT)(acc[mt][nt][r] + bv);
      }
    }
  }
}

__global__ __launch_bounds__(256) void gemm3_f16(
    const f16* __restrict__ A0, const f16* __restrict__ A1, const f16* __restrict__ A2,
    const f16* __restrict__ B0, const f16* __restrict__ B1, const f16* __restrict__ B2,
    const float* __restrict__ c0, const float* __restrict__ c1, const float* __restrict__ c2,
    f16* __restrict__ C0, f16* __restrict__ C1, f16* __restrict__ C2, int N, int K) {
  const f16* A = blockIdx.z == 0 ? A0 : blockIdx.z == 1 ? A1 : A2;
  const f16* Bt = blockIdx.z == 0 ? B0 : blockIdx.z == 1 ? B1 : B2;
  const float* bias = blockIdx.z == 0 ? c0 : blockIdx.z == 1 ? c1 : c2;
  f16* C = blockIdx.z == 0 ? C0 : blockIdx.z == 1 ? C1 : C2;
  gemm_body<f16>(A, Bt, bias, C, N, K);
}

__global__ __launch_bounds__(256) void gemm_f32(const f16* __restrict__ A,
                                                const f16* __restrict__ Bt,
                                                const float* __restrict__ bias,
                                                float* __restrict__ C, int N, int K) {
  gemm_body<float>(A, Bt, bias, C, N, K);
}

// ---------- LDS-tiled transpose: LV[(b,s)][(h,l)] -> LVt[(b,h)][l][s] ----------
__global__ __launch_bounds__(256) void transpose_lv(const f16* __restrict__ LV,
                                                    f16* __restrict__ LVt) {
  const int bh = blockIdx.y, b = bh >> 4, h = bh & 15;
  const int s0 = blockIdx.x * 64;
  __shared__ f16 tile[64][65];
  const int t = threadIdx.x;
  const int c0 = t & 63, r0 = t >> 6;
#pragma unroll
  for (int r = 0; r < 16; r++) {
    int s = r * 4 + r0;
    tile[s][c0] = LV[(size_t)(b * kS + s0 + s) * kHL + h * kL + c0];
  }
  __syncthreads();
#pragma unroll
  for (int r = 0; r < 16; r++) {
    int vl = r * 4 + r0;
    LVt[((size_t)bh * kL + vl) * kS + s0 + c0] = tile[c0][vl];
  }
}

// ---------- latent flash attention ----------
// Qlat/LK: [(b,s)][(h,l)] fp16 ; LVt: [(b,h)][l][s] fp16 ; Ctx: [(b,s)][(h,l)] fp16
__global__ __launch_bounds__(256) void attn(const f16* __restrict__ Qlat,
                                            const f16* __restrict__ LK,
                                            const f16* __restrict__ LVt,
                                            f16* __restrict__ Ctx) {
  const int bh = blockIdx.y, b = bh >> 4, h = bh & 15;
  const int q0 = blockIdx.x * 128;
  const int tid = threadIdx.x;
  const int w = tid >> 6, lane = tid & 63;
  const int quad = lane >> 4, l16 = lane & 15;

  __shared__ f16 sK[64 * 64];       // [kv][l]
  __shared__ f16 sV[64 * 64];       // [vl][kv]
  __shared__ f16 sP[4][32 * 64];    // per-wave P tile [q][kv]

  const f16* qbase = Qlat + (size_t)b * kS * kHL + h * kL;
  const f16* kbase = LK + (size_t)b * kS * kHL + h * kL;
  const f16* vbase = LVt + (size_t)bh * kL * kS;

  f16x8 aq[2][2];
#pragma unroll
  for (int mt = 0; mt < 2; mt++) {
#pragma unroll
    for (int ks = 0; ks < 2; ks++) {
      int row = q0 + w * 32 + mt * 16 + l16;
      aq[mt][ks] = *(const f16x8*)(qbase + (size_t)row * kHL + ks * 32 + quad * 8);
    }
  }

  f32x4 acc[2][4];
  for (int mt = 0; mt < 2; mt++)
    for (int nt = 0; nt < 4; nt++) acc[mt][nt] = (f32x4){0.f, 0.f, 0.f, 0.f};
  float mst[2][4], lst[2][4];
  for (int mt = 0; mt < 2; mt++)
    for (int r = 0; r < 4; r++) { mst[mt][r] = -3.0e38f; lst[mt][r] = 0.f; }

  const float scale = 0.08838834764831845f;  // 1/sqrt(128)
  const int rowA = lane >> 3, colA = (lane & 7) * 8;
  const int kv_end = q0 + 128;

  for (int kv0 = 0; kv0 < kv_end; kv0 += 64) {
    __syncthreads();
#pragma unroll
    for (int c = 0; c < 2; c++) {
      int rl = w * 16 + c * 8;
      load_lds16(kbase + (size_t)(kv0 + rl + rowA) * kHL + colA, &sK[rl * 64]);
      load_lds16(vbase + (size_t)(rl + rowA) * kS + kv0 + colA, &sV[rl * 64]);
    }
    __syncthreads();

    // scores: S = Q_lat @ K_lat^T
    f32x4 sc[2][4];
    for (int mt = 0; mt < 2; mt++)
      for (int nt = 0; nt < 4; nt++) sc[mt][nt] = (f32x4){0.f, 0.f, 0.f, 0.f};
#pragma unroll
    for (int ks = 0; ks < 2; ks++) {
      f16x8 bk[4];
#pragma unroll
      for (int nt = 0; nt < 4; nt++)
        bk[nt] = *(const f16x8*)&sK[(nt * 16 + l16) * 64 + ks * 32 + quad * 8];
#pragma unroll
      for (int mt = 0; mt < 2; mt++) {
#pragma unroll
        for (int nt = 0; nt < 4; nt++)
          sc[mt][nt] = mfma16(aq[mt][ks], bk[nt], sc[mt][nt]);
      }
    }

    // online softmax (per C-layout row: row = mt*16 + quad*4 + r, col = nt*16 + l16)
#pragma unroll
    for (int mt = 0; mt < 2; mt++) {
      float tmax[4] = {-3.0e38f, -3.0e38f, -3.0e38f, -3.0e38f};
#pragma unroll
      for (int nt = 0; nt < 4; nt++) {
        int kvg = kv0 + nt * 16 + l16;
#pragma unroll
        for (int r = 0; r < 4; r++) {
          int qg = q0 + w * 32 + mt * 16 + quad * 4 + r;
          float s = sc[mt][nt][r] * scale;
          if (kvg > qg) s = -1.0e30f;
          sc[mt][nt][r] = s;
          tmax[r] = fmaxf(tmax[r], s);
        }
      }
#pragma unroll
      for (int r = 0; r < 4; r++) {
        float t = tmax[r];
        t = fmaxf(t, __shfl_xor(t, 1));
        t = fmaxf(t, __shfl_xor(t, 2));
        t = fmaxf(t, __shfl_xor(t, 4));
        t = fmaxf(t, __shfl_xor(t, 8));
        tmax[r] = t;
      }
      float alpha[4], psum[4];
#pragma unroll
      for (int r = 0; r < 4; r++) {
        float mnew = fmaxf(mst[mt][r], tmax[r]);
        alpha[r] = __expf(mst[mt][r] - mnew);
        mst[mt][r] = mnew;
        psum[r] = 0.f;
      }
#pragma unroll
      for (int nt = 0; nt < 4; nt++) {
#pragma unroll
        for (int r = 0; r < 4; r++) {
          float p = __expf(sc[mt][nt][r] - mst[mt][r]);
          psum[r] += p;
          sP[w][(mt * 16 + quad * 4 + r) * 64 + nt * 16 + l16] = (f16)p;
        }
      }
#pragma unroll
      for (int r = 0; r < 4; r++) {
        float t = psum[r];
        t += __shfl_xor(t, 1);
        t += __shfl_xor(t, 2);
        t += __shfl_xor(t, 4);
        t += __shfl_xor(t, 8);
        lst[mt][r] = lst[mt][r] * alpha[r] + t;
      }
#pragma unroll
      for (int nt = 0; nt < 4; nt++) {
#pragma unroll
        for (int r = 0; r < 4; r++) acc[mt][nt][r] *= alpha[r];
      }
    }

    // PV: acc += P @ V  (P re-read from LDS in A-layout; same-wave DS ops are ordered)
#pragma unroll
    for (int ks = 0; ks < 2; ks++) {
      f16x8 ap[2], bv[4];
#pragma unroll
      for (int mt = 0; mt < 2; mt++)
        ap[mt] = *(const f16x8*)&sP[w][(mt * 16 + l16) * 64 + ks * 32 + quad * 8];
#pragma unroll
      for (int nt = 0; nt < 4; nt++)
        bv[nt] = *(const f16x8*)&sV[(nt * 16 + l16) * 64 + ks * 32 + quad * 8];
#pragma unroll
      for (int mt = 0; mt < 2; mt++) {
#pragma unroll
        for (int nt = 0; nt < 4; nt++)
          acc[mt][nt] = mfma16(ap[mt], bv[nt], acc[mt][nt]);
      }
    }
  }

#pragma unroll
  for (int mt = 0; mt < 2; mt++) {
#pragma unroll
    for (int r = 0; r < 4; r++) {
      float inv = 1.f / lst[mt][r];
      int qg = q0 + w * 32 + mt * 16 + quad * 4 + r;
      size_t base = (size_t)(b * kS + qg) * kHL + h * kL;
#pragma unroll
      for (int nt = 0; nt < 4; nt++)
        Ctx[base + nt * 16 + l16] = (f16)(acc[mt][nt][r] * inv);
    }
  }
}

extern "C" void kernel_launch(void* const* d_in, const int* in_sizes, int n_in,
                              void* d_out, int out_size, void* d_ws, size_t ws_size,
                              hipStream_t stream) {
  (void)in_sizes; (void)n_in; (void)out_size; (void)ws_size;
  const float* queries = (const float*)d_in[0];
  const float* keys    = (const float*)d_in[1];
  const float* values  = (const float*)d_in[2];
  const float* Wq      = (const float*)d_in[3];
  const float* bq      = (const float*)d_in[4];
  const float* Wlk     = (const float*)d_in[5];
  const float* blk     = (const float*)d_in[6];
  const float* Wlv     = (const float*)d_in[7];
  const float* blv     = (const float*)d_in[8];
  const float* Wkr     = (const float*)d_in[9];
  const float* Wvr     = (const float*)d_in[10];
  const float* Wout    = (const float*)d_in[11];
  const float* bout    = (const float*)d_in[12];

  char* ws = (char*)d_ws;
  size_t off = 0;
  auto alloc = [&](size_t bytes) {
    void* p = ws + off;
    off += (bytes + 255) & ~(size_t)255;
    return p;
  };
  f16* qb    = (f16*)alloc((size_t)kBS * kD * 2);
  f16* kb    = (f16*)alloc((size_t)kBS * kD * 2);
  f16* vb    = (f16*)alloc((size_t)kBS * kD * 2);
  f16* Wqlt  = (f16*)alloc((size_t)kHL * kD * 2);
  f16* Wlkt  = (f16*)alloc((size_t)kHL * kD * 2);
  f16* Wlvt  = (f16*)alloc((size_t)kHL * kD * 2);
  f16* W2t   = (f16*)alloc((size_t)kD * kHL * 2);
  float* bql = (float*)alloc(kHL * 4);
  f16* Qlat  = (f16*)alloc((size_t)kBS * kHL * 2);
  f16* LKb   = (f16*)alloc((size_t)kBS * kHL * 2);
  f16* LVb   = (f16*)alloc((size_t)kBS * kHL * 2);
  // alias dead input-cast buffers for post-GEMM intermediates:
  f16* LVtb = qb;  // LV transposed [b,h][l][s] — qb dead after gemm3
  f16* Ctx  = kb;  // attention output — kb dead after gemm3

  const int n4 = kBS * kD / 4;
  cast_f32_f16<<<n4 / 256, 256, 0, stream>>>(queries, qb, n4);
  cast_f32_f16<<<n4 / 256, 256, 0, stream>>>(keys, kb, n4);
  cast_f32_f16<<<n4 / 256, 256, 0, stream>>>(values, vb, n4);
  transpose_w<<<(kD * kHL) / 256, 256, 0, stream>>>(Wlk, Wlkt);
  transpose_w<<<(kD * kHL) / 256, 256, 0, stream>>>(Wlv, Wlvt);
  fold_q<<<(kHL * kD) / 256, 256, 0, stream>>>(Wq, Wkr, Wqlt);
  fold_bq<<<kHL / 256, 256, 0, stream>>>(bq, Wkr, bql);
  fold_out<<<(kD * kHL) / 256, 256, 0, stream>>>(Wvr, Wout, W2t);

  gemm3_f16<<<dim3(kHL / 128, kBS / 128, 3), 256, 0, stream>>>(
      qb, kb, vb, Wqlt, Wlkt, Wlvt, bql, blk, blv, Qlat, LKb, LVb, kHL, kD);

  transpose_lv<<<dim3(kS / 64, kB * kH), 256, 0, stream>>>(LVb, LVtb);
  attn<<<dim3(kS / 128, kB * kH), 256, 0, stream>>>(Qlat, LKb, LVtb, Ctx);
  gemm_f32<<<dim3(kD / 128, kBS / 128), 256, 0, stream>>>(Ctx, W2t, bout, (float*)d_out, kD, kHL);
}

// Round 3
// 505.407 us; speedup vs baseline: 1.5082x; 1.5082x over previous
//
#include <hip/hip_runtime.h>
#include <cstdint>
#include <cstddef>

typedef _Float16 f16;
typedef __attribute__((ext_vector_type(8))) _Float16 f16x8;
typedef __attribute__((ext_vector_type(4))) _Float16 f16x4;
typedef __attribute__((ext_vector_type(4))) float f32x4;

constexpr int kB  = 2;
constexpr int kS  = 2048;
constexpr int kD  = 2048;
constexpr int kH  = 16;
constexpr int kL  = 64;
constexpr int kHL = kH * kL;   // 1024
constexpr int kBS = kB * kS;   // 4096

__device__ __forceinline__ void load_lds16(const void* g, void* l) {
  __builtin_amdgcn_global_load_lds((const __attribute__((address_space(1))) void*)g,
                                   (__attribute__((address_space(3))) void*)l, 16, 0, 0);
}

__device__ __forceinline__ f32x4 mfma16(f16x8 a, f16x8 b, f32x4 c) {
  return __builtin_amdgcn_mfma_f32_16x16x32_f16(a, b, c, 0, 0, 0);
}

// ---------- fp32 -> fp16 cast, 4 elems/thread ----------
__global__ void cast_f32_f16(const float* __restrict__ in, f16* __restrict__ out, int n4) {
  int i = blockIdx.x * 256 + threadIdx.x;
  if (i >= n4) return;
  float4 f = ((const float4*)in)[i];
  f16x4 o; o[0] = (f16)f.x; o[1] = (f16)f.y; o[2] = (f16)f.z; o[3] = (f16)f.w;
  ((f16x4*)out)[i] = o;
}

// merged cast for q/k/v (grid.z selects tensor)
__global__ void cast3(const float* __restrict__ a, const float* __restrict__ b,
                      const float* __restrict__ c, f16* __restrict__ oa,
                      f16* __restrict__ ob, f16* __restrict__ oc) {
  const float* in = blockIdx.z == 0 ? a : blockIdx.z == 1 ? b : c;
  f16* out = blockIdx.z == 0 ? oa : blockIdx.z == 1 ? ob : oc;
  int i = blockIdx.x * 256 + threadIdx.x;
  float4 f = ((const float4*)in)[i];
  f16x4 o; o[0] = (f16)f.x; o[1] = (f16)f.y; o[2] = (f16)f.z; o[3] = (f16)f.w;
  ((f16x4*)out)[i] = o;
}

// ---------- LDS-tiled transpose-cast: in[R][C] fp32 -> out[C][R] fp16 ----------
__device__ __forceinline__ void transpose_body(const float* __restrict__ in,
                                               f16* __restrict__ out, int R, int C) {
  const int r0 = blockIdx.y * 64, c0 = blockIdx.x * 64;
  __shared__ float tile[64][65];
  const int t = threadIdx.x;
  const int cc = t & 63, rr = t >> 6;
#pragma unroll
  for (int p = 0; p < 16; p++) {
    int r = p * 4 + rr;
    tile[r][cc] = in[(size_t)(r0 + r) * C + c0 + cc];
  }
  __syncthreads();
#pragma unroll
  for (int p = 0; p < 16; p++) {
    int c = p * 4 + rr;
    out[(size_t)(c0 + c) * R + r0 + cc] = (f16)tile[cc][c];
  }
}

// Wlk / Wlv: [2048][1024] -> [1024][2048] fp16, z selects
__global__ __launch_bounds__(256) void transpose_lk_lv(const float* __restrict__ A0,
                                                       const float* __restrict__ A1,
                                                       f16* __restrict__ O0,
                                                       f16* __restrict__ O1) {
  transpose_body(blockIdx.z ? A1 : A0, blockIdx.z ? O1 : O0, 2048, 1024);
}

// Wout: [2048][2048] -> [2048][2048] fp16 transposed
__global__ __launch_bounds__(256) void transpose_wout(const float* __restrict__ in,
                                                      f16* __restrict__ out) {
  transpose_body(in, out, 2048, 2048);
}

// ---------- block-diagonal expansion: Wsrc[64][128] fp32 -> out[1024][2048] fp16 ----------
// out[(h,l)][k] = (k>>7 == h) ? Wsrc[l][k&127] : 0
__global__ void expand_w(const float* __restrict__ W0, const float* __restrict__ W1,
                         f16* __restrict__ O0, f16* __restrict__ O1) {
  const float* Wsrc = blockIdx.z ? W1 : W0;
  f16* out = blockIdx.z ? O1 : O0;
  int idx = blockIdx.x * 256 + threadIdx.x;  // 262144 = 1024 rows * 256 f16x8
  int hl = idx >> 8, k8 = idx & 255;
  int h = hl >> 6, l = hl & 63;
  f16x8 v;
#pragma unroll
  for (int j = 0; j < 8; j++) v[j] = (f16)0.f;
  if ((k8 >> 4) == h) {
    const float* src = Wsrc + l * 128 + (k8 & 15) * 8;
#pragma unroll
    for (int j = 0; j < 8; j++) v[j] = (f16)src[j];
  }
  ((f16x8*)out)[idx] = v;
}

__global__ void fold_bq(const float* __restrict__ bq, const float* __restrict__ Wkr,
                        float* __restrict__ bql) {
  int hl = blockIdx.x * 256 + threadIdx.x;
  if (hl >= kHL) return;
  int h = hl >> 6, l = hl & 63;
  float s = 0.f;
  for (int c = 0; c < 128; c++) s += bq[h * 128 + c] * Wkr[l * 128 + c];
  bql[hl] = s;
}

// ---------- MFMA GEMM: C[M,N] = A[M,K] @ Bt[N,K]^T (+ bias) ----------
// 128x128 tile, BK=64, 4 waves (2x2), global_load_lds staging.
template <typename OutT, bool HAS_BIAS>
__device__ __forceinline__ void gemm_body(const f16* __restrict__ A, const f16* __restrict__ Bt,
                                          const float* __restrict__ bias, OutT* __restrict__ C,
                                          int N, int K) {
  __shared__ f16 sA[128 * 64];
  __shared__ f16 sB[128 * 64];
  const int tid = threadIdx.x;
  const int w = tid >> 6, lane = tid & 63;
  const int quad = lane >> 4, l16 = lane & 15;
  const int wm = w >> 1, wn = w & 1;
  const int m0 = blockIdx.y * 128, n0 = blockIdx.x * 128;
  const int rowA = lane >> 3, colA = (lane & 7) * 8;

  f32x4 acc[4][4];
  for (int i = 0; i < 4; i++)
    for (int j = 0; j < 4; j++) acc[i][j] = (f32x4){0.f, 0.f, 0.f, 0.f};

  for (int k0 = 0; k0 < K; k0 += 64) {
    __syncthreads();
#pragma unroll
    for (int c = 0; c < 4; c++) {
      int rl = w * 32 + c * 8;
      load_lds16(A + (size_t)(m0 + rl + rowA) * K + k0 + colA, &sA[rl * 64]);
      load_lds16(Bt + (size_t)(n0 + rl + rowA) * K + k0 + colA, &sB[rl * 64]);
    }
    __syncthreads();
#pragma unroll
    for (int ks = 0; ks < 2; ks++) {
      f16x8 af[4], bfr[4];
#pragma unroll
      for (int mt = 0; mt < 4; mt++)
        af[mt] = *(const f16x8*)&sA[(wm * 64 + mt * 16 + l16) * 64 + ks * 32 + quad * 8];
#pragma unroll
      for (int nt = 0; nt < 4; nt++)
        bfr[nt] = *(const f16x8*)&sB[(wn * 64 + nt * 16 + l16) * 64 + ks * 32 + quad * 8];
#pragma unroll
      for (int mt = 0; mt < 4; mt++) {
#pragma unroll
        for (int nt = 0; nt < 4; nt++)
          acc[mt][nt] = mfma16(af[mt], bfr[nt], acc[mt][nt]);
      }
    }
  }
#pragma unroll
  for (int mt = 0; mt < 4; mt++) {
#pragma unroll
    for (int nt = 0; nt < 4; nt++) {
      int col = n0 + wn * 64 + nt * 16 + l16;
      float bv = HAS_BIAS ? bias[col] : 0.f;
#pragma unroll
      for (int r = 0; r < 4; r++) {
        int row = m0 + wm * 64 + mt * 16 + quad * 4 + r;
        C[(size_t)row * N + col] = (OutT)(acc[mt][nt][r] + bv);
      }
    }
  }
}

__global__ __launch_bounds__(256) void gemm3_f16(
    const f16* __restrict__ A0, const f16* __restrict__ A1, const f16* __restrict__ A2,
    const f16* __restrict__ B0, const f16* __restrict__ B1, const f16* __restrict__ B2,
    const float* __restrict__ c0, const float* __restrict__ c1, const float* __restrict__ c2,
    f16* __restrict__ C0, f16* __restrict__ C1, f16* __restrict__ C2, int N, int K) {
  const f16* A = blockIdx.z == 0 ? A0 : blockIdx.z == 1 ? A1 : A2;
  const f16* Bt = blockIdx.z == 0 ? B0 : blockIdx.z == 1 ? B1 : B2;
  const float* bias = blockIdx.z == 0 ? c0 : blockIdx.z == 1 ? c1 : c2;
  f16* C = blockIdx.z == 0 ? C0 : blockIdx.z == 1 ? C1 : C2;
  gemm_body<f16, true>(A, Bt, bias, C, N, K);
}

// z=0: Wqlt[1024][2048] = Wkr_exp[1024][2048] @ Wq16[2048][2048]^T
// z=1: W2t [2048][1024] = WoutT [2048][2048] @ Wvr_exp[1024][2048]^T
__global__ __launch_bounds__(256) void fold_gemms(
    const f16* __restrict__ Wkr_exp, const f16* __restrict__ Wq16, f16* __restrict__ Wqlt,
    const f16* __restrict__ WoutT, const f16* __restrict__ Wvr_exp, f16* __restrict__ W2t) {
  if (blockIdx.z == 0) {
    if (blockIdx.x >= 16 || blockIdx.y >= 8) return;
    gemm_body<f16, false>(Wkr_exp, Wq16, nullptr, Wqlt, 2048, 2048);
  } else {
    if (blockIdx.x >= 8 || blockIdx.y >= 16) return;
    gemm_body<f16, false>(WoutT, Wvr_exp, nullptr, W2t, 1024, 2048);
  }
}

__global__ __launch_bounds__(256) void gemm_f32(const f16* __restrict__ A,
                                                const f16* __restrict__ Bt,
                                                const float* __restrict__ bias,
                                                float* __restrict__ C, int N, int K) {
  gemm_body<float, true>(A, Bt, bias, C, N, K);
}

// ---------- LDS-tiled transpose: LV[(b,s)][(h,l)] -> LVt[(b,h)][l][s] ----------
__global__ __launch_bounds__(256) void transpose_lv(const f16* __restrict__ LV,
                                                    f16* __restrict__ LVt) {
  const int bh = blockIdx.y, b = bh >> 4, h = bh & 15;
  const int s0 = blockIdx.x * 64;
  __shared__ f16 tile[64][65];
  const int t = threadIdx.x;
  const int c0 = t & 63, r0 = t >> 6;
#pragma unroll
  for (int r = 0; r < 16; r++) {
    int s = r * 4 + r0;
    tile[s][c0] = LV[(size_t)(b * kS + s0 + s) * kHL + h * kL + c0];
  }
  __syncthreads();
#pragma unroll
  for (int r = 0; r < 16; r++) {
    int vl = r * 4 + r0;
    LVt[((size_t)bh * kL + vl) * kS + s0 + c0] = tile[c0][vl];
  }
}

// ---------- latent flash attention ----------
// Qlat/LK: [(b,s)][(h,l)] fp16 ; LVt: [(b,h)][l][s] fp16 ; Ctx: [(b,s)][(h,l)] fp16
__global__ __launch_bounds__(256) void attn(const f16* __restrict__ Qlat,
                                            const f16* __restrict__ LK,
                                            const f16* __restrict__ LVt,
                                            f16* __restrict__ Ctx) {
  const int bh = blockIdx.y, b = bh >> 4, h = bh & 15;
  const int q0 = blockIdx.x * 128;
  const int tid = threadIdx.x;
  const int w = tid >> 6, lane = tid & 63;
  const int quad = lane >> 4, l16 = lane & 15;

  __shared__ f16 sK[64 * 64];       // [kv][l]
  __shared__ f16 sV[64 * 64];       // [vl][kv]
  __shared__ f16 sP[4][32 * 64];    // per-wave P tile [q][kv]

  const f16* qbase = Qlat + (size_t)b * kS * kHL + h * kL;
  const f16* kbase = LK + (size_t)b * kS * kHL + h * kL;
  const f16* vbase = LVt + (size_t)bh * kL * kS;

  f16x8 aq[2][2];
#pragma unroll
  for (int mt = 0; mt < 2; mt++) {
#pragma unroll
    for (int ks = 0; ks < 2; ks++) {
      int row = q0 + w * 32 + mt * 16 + l16;
      aq[mt][ks] = *(const f16x8*)(qbase + (size_t)row * kHL + ks * 32 + quad * 8);
    }
  }

  f32x4 acc[2][4];
  for (int mt = 0; mt < 2; mt++)
    for (int nt = 0; nt < 4; nt++) acc[mt][nt] = (f32x4){0.f, 0.f, 0.f, 0.f};
  float mst[2][4], lst[2][4];
  for (int mt = 0; mt < 2; mt++)
    for (int r = 0; r < 4; r++) { mst[mt][r] = -3.0e38f; lst[mt][r] = 0.f; }

  const float scale = 0.08838834764831845f;  // 1/sqrt(128)
  const int rowA = lane >> 3, colA = (lane & 7) * 8;
  const int kv_end = q0 + 128;

  for (int kv0 = 0; kv0 < kv_end; kv0 += 64) {
    __syncthreads();
#pragma unroll
    for (int c = 0; c < 2; c++) {
      int rl = w * 16 + c * 8;
      load_lds16(kbase + (size_t)(kv0 + rl + rowA) * kHL + colA, &sK[rl * 64]);
      load_lds16(vbase + (size_t)(rl + rowA) * kS + kv0 + colA, &sV[rl * 64]);
    }
    __syncthreads();

    // scores: S = Q_lat @ K_lat^T
    f32x4 sc[2][4];
    for (int mt = 0; mt < 2; mt++)
      for (int nt = 0; nt < 4; nt++) sc[mt][nt] = (f32x4){0.f, 0.f, 0.f, 0.f};
#pragma unroll
    for (int ks = 0; ks < 2; ks++) {
      f16x8 bk[4];
#pragma unroll
      for (int nt = 0; nt < 4; nt++)
        bk[nt] = *(const f16x8*)&sK[(nt * 16 + l16) * 64 + ks * 32 + quad * 8];
#pragma unroll
      for (int mt = 0; mt < 2; mt++) {
#pragma unroll
        for (int nt = 0; nt < 4; nt++)
          sc[mt][nt] = mfma16(aq[mt][ks], bk[nt], sc[mt][nt]);
      }
    }

    // online softmax (C-layout: row = mt*16 + quad*4 + r, col = nt*16 + l16)
#pragma unroll
    for (int mt = 0; mt < 2; mt++) {
      float tmax[4] = {-3.0e38f, -3.0e38f, -3.0e38f, -3.0e38f};
#pragma unroll
      for (int nt = 0; nt < 4; nt++) {
        int kvg = kv0 + nt * 16 + l16;
#pragma unroll
        for (int r = 0; r < 4; r++) {
          int qg = q0 + w * 32 + mt * 16 + quad * 4 + r;
          float s = sc[mt][nt][r] * scale;
          if (kvg > qg) s = -1.0e30f;
          sc[mt][nt][r] = s;
          tmax[r] = fmaxf(tmax[r], s);
        }
      }
#pragma unroll
      for (int r = 0; r < 4; r++) {
        float t = tmax[r];
        t = fmaxf(t, __shfl_xor(t, 1));
        t = fmaxf(t, __shfl_xor(t, 2));
        t = fmaxf(t, __shfl_xor(t, 4));
        t = fmaxf(t, __shfl_xor(t, 8));
        tmax[r] = t;
      }
      float alpha[4], psum[4];
#pragma unroll
      for (int r = 0; r < 4; r++) {
        float mnew = fmaxf(mst[mt][r], tmax[r]);
        alpha[r] = __expf(mst[mt][r] - mnew);
        mst[mt][r] = mnew;
        psum[r] = 0.f;
      }
#pragma unroll
      for (int nt = 0; nt < 4; nt++) {
#pragma unroll
        for (int r = 0; r < 4; r++) {
          float p = __expf(sc[mt][nt][r] - mst[mt][r]);
          psum[r] += p;
          sP[w][(mt * 16 + quad * 4 + r) * 64 + nt * 16 + l16] = (f16)p;
        }
      }
#pragma unroll
      for (int r = 0; r < 4; r++) {
        float t = psum[r];
        t += __shfl_xor(t, 1);
        t += __shfl_xor(t, 2);
        t += __shfl_xor(t, 4);
        t += __shfl_xor(t, 8);
        lst[mt][r] = lst[mt][r] * alpha[r] + t;
      }
#pragma unroll
      for (int nt = 0; nt < 4; nt++) {
#pragma unroll
        for (int r = 0; r < 4; r++) acc[mt][nt][r] *= alpha[r];
      }
    }

    // PV: acc += P @ V  (P re-read from LDS in A-layout; same-wave DS ops are ordered)
#pragma unroll
    for (int ks = 0; ks < 2; ks++) {
      f16x8 ap[2], bv[4];
#pragma unroll
      for (int mt = 0; mt < 2; mt++)
        ap[mt] = *(const f16x8*)&sP[w][(mt * 16 + l16) * 64 + ks * 32 + quad * 8];
#pragma unroll
      for (int nt = 0; nt < 4; nt++)
        bv[nt] = *(const f16x8*)&sV[(nt * 16 + l16) * 64 + ks * 32 + quad * 8];
#pragma unroll
      for (int mt = 0; mt < 2; mt++) {
#pragma unroll
        for (int nt = 0; nt < 4; nt++)
          acc[mt][nt] = mfma16(ap[mt], bv[nt], acc[mt][nt]);
      }
    }
  }

#pragma unroll
  for (int mt = 0; mt < 2; mt++) {
#pragma unroll
    for (int r = 0; r < 4; r++) {
      float inv = 1.f / lst[mt][r];
      int qg = q0 + w * 32 + mt * 16 + quad * 4 + r;
      size_t base = (size_t)(b * kS + qg) * kHL + h * kL;
#pragma unroll
      for (int nt = 0; nt < 4; nt++)
        Ctx[base + nt * 16 + l16] = (f16)(acc[mt][nt][r] * inv);
    }
  }
}

extern "C" void kernel_launch(void* const* d_in, const int* in_sizes, int n_in,
                              void* d_out, int out_size, void* d_ws, size_t ws_size,
                              hipStream_t stream) {
  (void)in_sizes; (void)n_in; (void)out_size; (void)ws_size;
  const float* queries = (const float*)d_in[0];
  const float* keys    = (const float*)d_in[1];
  const float* values  = (const float*)d_in[2];
  const float* Wq      = (const float*)d_in[3];
  const float* bq      = (const float*)d_in[4];
  const float* Wlk     = (const float*)d_in[5];
  const float* blk     = (const float*)d_in[6];
  const float* Wlv     = (const float*)d_in[7];
  const float* blv     = (const float*)d_in[8];
  const float* Wkr     = (const float*)d_in[9];
  const float* Wvr     = (const float*)d_in[10];
  const float* Wout    = (const float*)d_in[11];
  const float* bout    = (const float*)d_in[12];

  char* ws = (char*)d_ws;
  size_t off = 0;
  auto alloc = [&](size_t bytes) {
    void* p = ws + off;
    off += (bytes + 255) & ~(size_t)255;
    return p;
  };
  f16* qb    = (f16*)alloc((size_t)kBS * kD * 2);
  f16* kb    = (f16*)alloc((size_t)kBS * kD * 2);
  f16* vb    = (f16*)alloc((size_t)kBS * kD * 2);
  f16* Wqlt  = (f16*)alloc((size_t)kHL * kD * 2);
  f16* Wlkt  = (f16*)alloc((size_t)kHL * kD * 2);
  f16* Wlvt  = (f16*)alloc((size_t)kHL * kD * 2);
  f16* W2t   = (f16*)alloc((size_t)kD * kHL * 2);
  float* bql = (float*)alloc(kHL * 4);
  f16* Qlat  = (f16*)alloc((size_t)kBS * kHL * 2);
  f16* LKb   = (f16*)alloc((size_t)kBS * kHL * 2);
  f16* LVb   = (f16*)alloc((size_t)kBS * kHL * 2);
  // prep-only buffers alias post-fold intermediates (dead by the time those are written):
  f16* Wq16    = Qlat;            // 8 MB (kD*kD f16), consumed by fold_gemms before gemm3 writes Qlat
  f16* WoutT   = LKb;             // 8 MB, consumed by fold_gemms before gemm3 writes LKb
  f16* Wkr_exp = LVb;                           // kHL*kD f16 = 4 MB
  f16* Wvr_exp = LVb + (size_t)kHL * kD;        // next kHL*kD f16 = 4 MB (ELEMENT offset — bugfix)
  // input-cast buffers alias post-attn intermediates:
  f16* LVtb = qb;  // LV transposed [b,h][l][s] — qb dead after gemm3
  f16* Ctx  = kb;  // attention output — kb dead after gemm3

  const int n4 = kBS * kD / 4;
  cast3<<<dim3(n4 / 256, 1, 3), 256, 0, stream>>>(queries, keys, values, qb, kb, vb);
  cast_f32_f16<<<(kD * kD / 4) / 256, 256, 0, stream>>>(Wq, Wq16, kD * kD / 4);
  transpose_lk_lv<<<dim3(kHL / 64, kD / 64, 2), 256, 0, stream>>>(Wlk, Wlv, Wlkt, Wlvt);
  transpose_wout<<<dim3(kD / 64, kD / 64), 256, 0, stream>>>(Wout, WoutT);
  expand_w<<<dim3((kHL * kD / 8) / 256, 1, 2), 256, 0, stream>>>(Wkr, Wvr, Wkr_exp, Wvr_exp);
  fold_bq<<<kHL / 256, 256, 0, stream>>>(bq, Wkr, bql);

  fold_gemms<<<dim3(16, 16, 2), 256, 0, stream>>>(Wkr_exp, Wq16, Wqlt, WoutT, Wvr_exp, W2t);

  gemm3_f16<<<dim3(kHL / 128, kBS / 128, 3), 256, 0, stream>>>(
      qb, kb, vb, Wqlt, Wlkt, Wlvt, bql, blk, blv, Qlat, LKb, LVb, kHL, kD);

  transpose_lv<<<dim3(kS / 64, kB * kH), 256, 0, stream>>>(LVb, LVtb);
  attn<<<dim3(kS / 128, kB * kH), 256, 0, stream>>>(Qlat, LKb, LVtb, Ctx);
  gemm_f32<<<dim3(kD / 128, kBS / 128), 256, 0, stream>>>(Ctx, W2t, bout, (float*)d_out, kD, kHL);
}

// Round 4
// 456.278 us; speedup vs baseline: 1.6706x; 1.1077x over previous
//
#include <hip/hip_runtime.h>
#include <cstdint>
#include <cstddef>

typedef _Float16 f16;
typedef __attribute__((ext_vector_type(8))) _Float16 f16x8;
typedef __attribute__((ext_vector_type(4))) _Float16 f16x4;
typedef __attribute__((ext_vector_type(4))) float f32x4;

constexpr int kB  = 2;
constexpr int kS  = 2048;
constexpr int kD  = 2048;
constexpr int kH  = 16;
constexpr int kL  = 64;
constexpr int kHL = kH * kL;   // 1024
constexpr int kBS = kB * kS;   // 4096

__device__ __forceinline__ void load_lds16(const void* g, void* l) {
  __builtin_amdgcn_global_load_lds((const __attribute__((address_space(1))) void*)g,
                                   (__attribute__((address_space(3))) void*)l, 16, 0, 0);
}

__device__ __forceinline__ f32x4 mfma16(f16x8 a, f16x8 b, f32x4 c) {
  return __builtin_amdgcn_mfma_f32_16x16x32_f16(a, b, c, 0, 0, 0);
}

// ---------- fp32 -> fp16 cast, 4 elems/thread ----------
__global__ void cast_f32_f16(const float* __restrict__ in, f16* __restrict__ out, int n4) {
  int i = blockIdx.x * 256 + threadIdx.x;
  if (i >= n4) return;
  float4 f = ((const float4*)in)[i];
  f16x4 o; o[0] = (f16)f.x; o[1] = (f16)f.y; o[2] = (f16)f.z; o[3] = (f16)f.w;
  ((f16x4*)out)[i] = o;
}

// merged cast for q/k/v (grid.z selects tensor)
__global__ void cast3(const float* __restrict__ a, const float* __restrict__ b,
                      const float* __restrict__ c, f16* __restrict__ oa,
                      f16* __restrict__ ob, f16* __restrict__ oc) {
  const float* in = blockIdx.z == 0 ? a : blockIdx.z == 1 ? b : c;
  f16* out = blockIdx.z == 0 ? oa : blockIdx.z == 1 ? ob : oc;
  int i = blockIdx.x * 256 + threadIdx.x;
  float4 f = ((const float4*)in)[i];
  f16x4 o; o[0] = (f16)f.x; o[1] = (f16)f.y; o[2] = (f16)f.z; o[3] = (f16)f.w;
  ((f16x4*)out)[i] = o;
}

// ---------- LDS-tiled transpose-cast: in[R][C] fp32 -> out[C][R] fp16 ----------
__device__ __forceinline__ void transpose_body(const float* __restrict__ in,
                                               f16* __restrict__ out, int R, int C) {
  const int r0 = blockIdx.y * 64, c0 = blockIdx.x * 64;
  __shared__ float tile[64][65];
  const int t = threadIdx.x;
  const int cc = t & 63, rr = t >> 6;
#pragma unroll
  for (int p = 0; p < 16; p++) {
    int r = p * 4 + rr;
    tile[r][cc] = in[(size_t)(r0 + r) * C + c0 + cc];
  }
  __syncthreads();
#pragma unroll
  for (int p = 0; p < 16; p++) {
    int c = p * 4 + rr;
    out[(size_t)(c0 + c) * R + r0 + cc] = (f16)tile[cc][c];
  }
}

// Wlk / Wlv: [2048][1024] -> [1024][2048] fp16, z selects
__global__ __launch_bounds__(256) void transpose_lk_lv(const float* __restrict__ A0,
                                                       const float* __restrict__ A1,
                                                       f16* __restrict__ O0,
                                                       f16* __restrict__ O1) {
  transpose_body(blockIdx.z ? A1 : A0, blockIdx.z ? O1 : O0, 2048, 1024);
}

// Wout: [2048][2048] -> [2048][2048] fp16 transposed
__global__ __launch_bounds__(256) void transpose_wout(const float* __restrict__ in,
                                                      f16* __restrict__ out) {
  transpose_body(in, out, 2048, 2048);
}

// ---------- block-diagonal expansion: Wsrc[64][128] fp32 -> out[1024][2048] fp16 ----------
__global__ void expand_w(const float* __restrict__ W0, const float* __restrict__ W1,
                         f16* __restrict__ O0, f16* __restrict__ O1) {
  const float* Wsrc = blockIdx.z ? W1 : W0;
  f16* out = blockIdx.z ? O1 : O0;
  int idx = blockIdx.x * 256 + threadIdx.x;  // 262144 = 1024 rows * 256 f16x8
  int hl = idx >> 8, k8 = idx & 255;
  int h = hl >> 6, l = hl & 63;
  f16x8 v;
#pragma unroll
  for (int j = 0; j < 8; j++) v[j] = (f16)0.f;
  if ((k8 >> 4) == h) {
    const float* src = Wsrc + l * 128 + (k8 & 15) * 8;
#pragma unroll
    for (int j = 0; j < 8; j++) v[j] = (f16)src[j];
  }
  ((f16x8*)out)[idx] = v;
}

__global__ void fold_bq(const float* __restrict__ bq, const float* __restrict__ Wkr,
                        float* __restrict__ bql) {
  int hl = blockIdx.x * 256 + threadIdx.x;
  if (hl >= kHL) return;
  int h = hl >> 6, l = hl & 63;
  float s = 0.f;
  for (int c = 0; c < 128; c++) s += bq[h * 128 + c] * Wkr[l * 128 + c];
  bql[hl] = s;
}

// ---------- MFMA GEMM: C[M,N] = A[M,K] @ Bt[N,K]^T (+ bias) ----------
template <typename OutT, bool HAS_BIAS>
__device__ __forceinline__ void gemm_body(const f16* __restrict__ A, const f16* __restrict__ Bt,
                                          const float* __restrict__ bias, OutT* __restrict__ C,
                                          int N, int K) {
  __shared__ f16 sA[128 * 64];
  __shared__ f16 sB[128 * 64];
  const int tid = threadIdx.x;
  const int w = tid >> 6, lane = tid & 63;
  const int quad = lane >> 4, l16 = lane & 15;
  const int wm = w >> 1, wn = w & 1;
  const int m0 = blockIdx.y * 128, n0 = blockIdx.x * 128;
  const int rowA = lane >> 3, colA = (lane & 7) * 8;

  f32x4 acc[4][4];
  for (int i = 0; i < 4; i++)
    for (int j = 0; j < 4; j++) acc[i][j] = (f32x4){0.f, 0.f, 0.f, 0.f};

  for (int k0 = 0; k0 < K; k0 += 64) {
    __syncthreads();
#pragma unroll
    for (int c = 0; c < 4; c++) {
      int rl = w * 32 + c * 8;
      load_lds16(A + (size_t)(m0 + rl + rowA) * K + k0 + colA, &sA[rl * 64]);
      load_lds16(Bt + (size_t)(n0 + rl + rowA) * K + k0 + colA, &sB[rl * 64]);
    }
    __syncthreads();
#pragma unroll
    for (int ks = 0; ks < 2; ks++) {
      f16x8 af[4], bfr[4];
#pragma unroll
      for (int mt = 0; mt < 4; mt++)
        af[mt] = *(const f16x8*)&sA[(wm * 64 + mt * 16 + l16) * 64 + ks * 32 + quad * 8];
#pragma unroll
      for (int nt = 0; nt < 4; nt++)
        bfr[nt] = *(const f16x8*)&sB[(wn * 64 + nt * 16 + l16) * 64 + ks * 32 + quad * 8];
#pragma unroll
      for (int mt = 0; mt < 4; mt++) {
#pragma unroll
        for (int nt = 0; nt < 4; nt++)
          acc[mt][nt] = mfma16(af[mt], bfr[nt], acc[mt][nt]);
      }
    }
  }
#pragma unroll
  for (int mt = 0; mt < 4; mt++) {
#pragma unroll
    for (int nt = 0; nt < 4; nt++) {
      int col = n0 + wn * 64 + nt * 16 + l16;
      float bv = HAS_BIAS ? bias[col] : 0.f;
#pragma unroll
      for (int r = 0; r < 4; r++) {
        int row = m0 + wm * 64 + mt * 16 + quad * 4 + r;
        C[(size_t)row * N + col] = (OutT)(acc[mt][nt][r] + bv);
      }
    }
  }
}

__global__ __launch_bounds__(256) void gemm3_f16(
    const f16* __restrict__ A0, const f16* __restrict__ A1, const f16* __restrict__ A2,
    const f16* __restrict__ B0, const f16* __restrict__ B1, const f16* __restrict__ B2,
    const float* __restrict__ c0, const float* __restrict__ c1, const float* __restrict__ c2,
    f16* __restrict__ C0, f16* __restrict__ C1, f16* __restrict__ C2, int N, int K) {
  const f16* A = blockIdx.z == 0 ? A0 : blockIdx.z == 1 ? A1 : A2;
  const f16* Bt = blockIdx.z == 0 ? B0 : blockIdx.z == 1 ? B1 : B2;
  const float* bias = blockIdx.z == 0 ? c0 : blockIdx.z == 1 ? c1 : c2;
  f16* C = blockIdx.z == 0 ? C0 : blockIdx.z == 1 ? C1 : C2;
  gemm_body<f16, true>(A, Bt, bias, C, N, K);
}

// z=0: Wqlt[1024][2048] = Wkr_exp[1024][2048] @ Wq16[2048][2048]^T
// z=1: W2t [2048][1024] = WoutT [2048][2048] @ Wvr_exp[1024][2048]^T
__global__ __launch_bounds__(256) void fold_gemms(
    const f16* __restrict__ Wkr_exp, const f16* __restrict__ Wq16, f16* __restrict__ Wqlt,
    const f16* __restrict__ WoutT, const f16* __restrict__ Wvr_exp, f16* __restrict__ W2t) {
  if (blockIdx.z == 0) {
    if (blockIdx.x >= 16 || blockIdx.y >= 8) return;
    gemm_body<f16, false>(Wkr_exp, Wq16, nullptr, Wqlt, 2048, 2048);
  } else {
    if (blockIdx.x >= 8 || blockIdx.y >= 16) return;
    gemm_body<f16, false>(WoutT, Wvr_exp, nullptr, W2t, 1024, 2048);
  }
}

__global__ __launch_bounds__(256) void gemm_f32(const f16* __restrict__ A,
                                                const f16* __restrict__ Bt,
                                                const float* __restrict__ bias,
                                                float* __restrict__ C, int N, int K) {
  gemm_body<float, true>(A, Bt, bias, C, N, K);
}

// ---------- LDS-tiled transpose: LV[(b,s)][(h,l)] -> LVt[(b,h)][l][s] ----------
__global__ __launch_bounds__(256) void transpose_lv(const f16* __restrict__ LV,
                                                    f16* __restrict__ LVt) {
  const int bh = blockIdx.y, b = bh >> 4, h = bh & 15;
  const int s0 = blockIdx.x * 64;
  __shared__ f16 tile[64][65];
  const int t = threadIdx.x;
  const int c0 = t & 63, r0 = t >> 6;
#pragma unroll
  for (int r = 0; r < 16; r++) {
    int s = r * 4 + r0;
    tile[s][c0] = LV[(size_t)(b * kS + s0 + s) * kHL + h * kL + c0];
  }
  __syncthreads();
#pragma unroll
  for (int r = 0; r < 16; r++) {
    int vl = r * 4 + r0;
    LVt[((size_t)bh * kL + vl) * kS + s0 + c0] = tile[c0][vl];
  }
}

// ---------- latent flash attention (load-balanced causal) ----------
// 64-row q-tiles; block processes complementary tiles (p, 31-p) => every block
// does exactly 33 kv-iterations. 512 blocks = 2/CU for wave-level overlap.
// Qlat/LK: [(b,s)][(h,l)] fp16 ; LVt: [(b,h)][l][s] fp16 ; Ctx: [(b,s)][(h,l)] fp16
__global__ __launch_bounds__(256) void attn(const f16* __restrict__ Qlat,
                                            const f16* __restrict__ LK,
                                            const f16* __restrict__ LVt,
                                            f16* __restrict__ Ctx) {
  const int bh = blockIdx.y, b = bh >> 4, h = bh & 15;
  const int pair = blockIdx.x;  // 0..15
  const int tid = threadIdx.x;
  const int w = tid >> 6, lane = tid & 63;
  const int quad = lane >> 4, l16 = lane & 15;

  __shared__ f16 sK[64 * 64];     // [kv][l]
  __shared__ f16 sV[64 * 64];     // [vl][kv]
  __shared__ f16 sP[4][16 * 72];  // per-wave P tile [q][kv], stride 72 kills bank conflicts

  const f16* qbase = Qlat + (size_t)b * kS * kHL + h * kL;
  const f16* kbase = LK + (size_t)b * kS * kHL + h * kL;
  const f16* vbase = LVt + (size_t)bh * kL * kS;

  const float scale = 0.08838834764831845f;  // 1/sqrt(128)
  const int rowA = lane >> 3, colA = (lane & 7) * 8;

#pragma unroll
  for (int which = 0; which < 2; which++) {
    const int t = which ? (31 - pair) : pair;
    const int q0 = t * 64;
    const int qrow = q0 + w * 16 + l16;  // this wave's A-fragment row

    f16x8 aq[2];
#pragma unroll
    for (int ks = 0; ks < 2; ks++)
      aq[ks] = *(const f16x8*)(qbase + (size_t)qrow * kHL + ks * 32 + quad * 8);

    f32x4 acc[4];
    for (int nt = 0; nt < 4; nt++) acc[nt] = (f32x4){0.f, 0.f, 0.f, 0.f};
    float mst[4], lst[4];
    for (int r = 0; r < 4; r++) { mst[r] = -3.0e38f; lst[r] = 0.f; }

    for (int kv0 = 0; kv0 <= q0; kv0 += 64) {
      __syncthreads();
#pragma unroll
      for (int c = 0; c < 2; c++) {
        int rl = w * 16 + c * 8;
        load_lds16(kbase + (size_t)(kv0 + rl + rowA) * kHL + colA, &sK[rl * 64]);
        load_lds16(vbase + (size_t)(rl + rowA) * kS + kv0 + colA, &sV[rl * 64]);
      }
      __syncthreads();

      // scores: S = Q_lat @ K_lat^T   (wave's 16 q-rows x 64 kv)
      f32x4 sc[4];
      for (int nt = 0; nt < 4; nt++) sc[nt] = (f32x4){0.f, 0.f, 0.f, 0.f};
#pragma unroll
      for (int ks = 0; ks < 2; ks++) {
        f16x8 bk[4];
#pragma unroll
        for (int nt = 0; nt < 4; nt++)
          bk[nt] = *(const f16x8*)&sK[(nt * 16 + l16) * 64 + ks * 32 + quad * 8];
#pragma unroll
        for (int nt = 0; nt < 4; nt++) sc[nt] = mfma16(aq[ks], bk[nt], sc[nt]);
      }

      // online softmax (C-layout: row = quad*4 + r, col = nt*16 + l16)
      float tmax[4] = {-3.0e38f, -3.0e38f, -3.0e38f, -3.0e38f};
      if (kv0 == q0) {  // diagonal tile: apply causal mask
#pragma unroll
        for (int nt = 0; nt < 4; nt++) {
          int kvg = kv0 + nt * 16 + l16;
#pragma unroll
          for (int r = 0; r < 4; r++) {
            int qg = q0 + w * 16 + quad * 4 + r;
            float s = sc[nt][r] * scale;
            if (kvg > qg) s = -1.0e30f;
            sc[nt][r] = s;
            tmax[r] = fmaxf(tmax[r], s);
          }
        }
      } else {
#pragma unroll
        for (int nt = 0; nt < 4; nt++) {
#pragma unroll
          for (int r = 0; r < 4; r++) {
            float s = sc[nt][r] * scale;
            sc[nt][r] = s;
            tmax[r] = fmaxf(tmax[r], s);
          }
        }
      }
#pragma unroll
      for (int r = 0; r < 4; r++) {
        float tm = tmax[r];
        tm = fmaxf(tm, __shfl_xor(tm, 1));
        tm = fmaxf(tm, __shfl_xor(tm, 2));
        tm = fmaxf(tm, __shfl_xor(tm, 4));
        tm = fmaxf(tm, __shfl_xor(tm, 8));
        tmax[r] = tm;
      }
      float alpha[4], psum[4];
#pragma unroll
      for (int r = 0; r < 4; r++) {
        float mnew = fmaxf(mst[r], tmax[r]);
        alpha[r] = __expf(mst[r] - mnew);
        mst[r] = mnew;
        psum[r] = 0.f;
      }
#pragma unroll
      for (int nt = 0; nt < 4; nt++) {
#pragma unroll
        for (int r = 0; r < 4; r++) {
          float p = __expf(sc[nt][r] - mst[r]);
          psum[r] += p;
          sP[w][(quad * 4 + r) * 72 + nt * 16 + l16] = (f16)p;
        }
      }
#pragma unroll
      for (int r = 0; r < 4; r++) {
        float s = psum[r];
        s += __shfl_xor(s, 1);
        s += __shfl_xor(s, 2);
        s += __shfl_xor(s, 4);
        s += __shfl_xor(s, 8);
        lst[r] = lst[r] * alpha[r] + s;
      }
#pragma unroll
      for (int nt = 0; nt < 4; nt++) {
#pragma unroll
        for (int r = 0; r < 4; r++) acc[nt][r] *= alpha[r];
      }

      // PV: acc += P @ V  (P via LDS: C-layout -> A-layout; same-wave DS ops ordered)
#pragma unroll
      for (int ks = 0; ks < 2; ks++) {
        f16x8 ap = *(const f16x8*)&sP[w][l16 * 72 + ks * 32 + quad * 8];
        f16x8 bv[4];
#pragma unroll
        for (int nt = 0; nt < 4; nt++)
          bv[nt] = *(const f16x8*)&sV[(nt * 16 + l16) * 64 + ks * 32 + quad * 8];
#pragma unroll
        for (int nt = 0; nt < 4; nt++) acc[nt] = mfma16(ap, bv[nt], acc[nt]);
      }
    }

#pragma unroll
    for (int r = 0; r < 4; r++) {
      float inv = 1.f / lst[r];
      int qg = q0 + w * 16 + quad * 4 + r;
      size_t base = (size_t)(b * kS + qg) * kHL + h * kL;
#pragma unroll
      for (int nt = 0; nt < 4; nt++)
        Ctx[base + nt * 16 + l16] = (f16)(acc[nt][r] * inv);
    }
  }
}

extern "C" void kernel_launch(void* const* d_in, const int* in_sizes, int n_in,
                              void* d_out, int out_size, void* d_ws, size_t ws_size,
                              hipStream_t stream) {
  (void)in_sizes; (void)n_in; (void)out_size; (void)ws_size;
  const float* queries = (const float*)d_in[0];
  const float* keys    = (const float*)d_in[1];
  const float* values  = (const float*)d_in[2];
  const float* Wq      = (const float*)d_in[3];
  const float* bq      = (const float*)d_in[4];
  const float* Wlk     = (const float*)d_in[5];
  const float* blk     = (const float*)d_in[6];
  const float* Wlv     = (const float*)d_in[7];
  const float* blv     = (const float*)d_in[8];
  const float* Wkr     = (const float*)d_in[9];
  const float* Wvr     = (const float*)d_in[10];
  const float* Wout    = (const float*)d_in[11];
  const float* bout    = (const float*)d_in[12];

  char* ws = (char*)d_ws;
  size_t off = 0;
  auto alloc = [&](size_t bytes) {
    void* p = ws + off;
    off += (bytes + 255) & ~(size_t)255;
    return p;
  };
  f16* qb    = (f16*)alloc((size_t)kBS * kD * 2);
  f16* kb    = (f16*)alloc((size_t)kBS * kD * 2);
  f16* vb    = (f16*)alloc((size_t)kBS * kD * 2);
  f16* Wqlt  = (f16*)alloc((size_t)kHL * kD * 2);
  f16* Wlkt  = (f16*)alloc((size_t)kHL * kD * 2);
  f16* Wlvt  = (f16*)alloc((size_t)kHL * kD * 2);
  f16* W2t   = (f16*)alloc((size_t)kD * kHL * 2);
  float* bql = (float*)alloc(kHL * 4);
  f16* Qlat  = (f16*)alloc((size_t)kBS * kHL * 2);
  f16* LKb   = (f16*)alloc((size_t)kBS * kHL * 2);
  f16* LVb   = (f16*)alloc((size_t)kBS * kHL * 2);
  // prep-only buffers alias post-fold intermediates (dead by the time those are written):
  f16* Wq16    = Qlat;            // 8 MB (kD*kD f16), consumed by fold_gemms before gemm3 writes Qlat
  f16* WoutT   = LKb;             // 8 MB, consumed by fold_gemms before gemm3 writes LKb
  f16* Wkr_exp = LVb;                           // kHL*kD f16 = 4 MB
  f16* Wvr_exp = LVb + (size_t)kHL * kD;        // next kHL*kD f16 = 4 MB (element offset)
  // input-cast buffers alias post-attn intermediates:
  f16* LVtb = qb;  // LV transposed [b,h][l][s] — qb dead after gemm3
  f16* Ctx  = kb;  // attention output — kb dead after gemm3

  const int n4 = kBS * kD / 4;
  cast3<<<dim3(n4 / 256, 1, 3), 256, 0, stream>>>(queries, keys, values, qb, kb, vb);
  cast_f32_f16<<<(kD * kD / 4) / 256, 256, 0, stream>>>(Wq, Wq16, kD * kD / 4);
  transpose_lk_lv<<<dim3(kHL / 64, kD / 64, 2), 256, 0, stream>>>(Wlk, Wlv, Wlkt, Wlvt);
  transpose_wout<<<dim3(kD / 64, kD / 64), 256, 0, stream>>>(Wout, WoutT);
  expand_w<<<dim3((kHL * kD / 8) / 256, 1, 2), 256, 0, stream>>>(Wkr, Wvr, Wkr_exp, Wvr_exp);
  fold_bq<<<kHL / 256, 256, 0, stream>>>(bq, Wkr, bql);

  fold_gemms<<<dim3(16, 16, 2), 256, 0, stream>>>(Wkr_exp, Wq16, Wqlt, WoutT, Wvr_exp, W2t);

  gemm3_f16<<<dim3(kHL / 128, kBS / 128, 3), 256, 0, stream>>>(
      qb, kb, vb, Wqlt, Wlkt, Wlvt, bql, blk, blv, Qlat, LKb, LVb, kHL, kD);

  transpose_lv<<<dim3(kS / 64, kB * kH), 256, 0, stream>>>(LVb, LVtb);
  attn<<<dim3(16, kB * kH), 256, 0, stream>>>(Qlat, LKb, LVtb, Ctx);
  gemm_f32<<<dim3(kD / 128, kBS / 128), 256, 0, stream>>>(Ctx, W2t, bout, (float*)d_out, kD, kHL);
}

// Round 5
// 419.003 us; speedup vs baseline: 1.8192x; 1.0890x over previous
//
#include <hip/hip_runtime.h>
#include <cstdint>
#include <cstddef>

typedef _Float16 f16;
typedef __attribute__((ext_vector_type(8))) _Float16 f16x8;
typedef __attribute__((ext_vector_type(4))) _Float16 f16x4;
typedef __attribute__((ext_vector_type(4))) float f32x4;

constexpr int kB  = 2;
constexpr int kS  = 2048;
constexpr int kD  = 2048;
constexpr int kH  = 16;
constexpr int kL  = 64;
constexpr int kHL = kH * kL;   // 1024
constexpr int kBS = kB * kS;   // 4096

__device__ __forceinline__ void load_lds16(const void* g, void* l) {
  __builtin_amdgcn_global_load_lds((const __attribute__((address_space(1))) void*)g,
                                   (__attribute__((address_space(3))) void*)l, 16, 0, 0);
}

__device__ __forceinline__ f32x4 mfma16(f16x8 a, f16x8 b, f32x4 c) {
  return __builtin_amdgcn_mfma_f32_16x16x32_f16(a, b, c, 0, 0, 0);
}

// ---------- merged fp32 -> fp16 cast: z=0..2 q/k/v (8M elems), z=3 Wq (4M elems) ----------
__global__ void cast4(const float* __restrict__ a, const float* __restrict__ b,
                      const float* __restrict__ c, const float* __restrict__ d,
                      f16* __restrict__ oa, f16* __restrict__ ob,
                      f16* __restrict__ oc, f16* __restrict__ od) {
  const int z = blockIdx.z;
  int i = blockIdx.x * 256 + threadIdx.x;
  if (z == 3 && i >= kD * kD / 4) return;
  const float* in = z == 0 ? a : z == 1 ? b : z == 2 ? c : d;
  f16* out = z == 0 ? oa : z == 1 ? ob : z == 2 ? oc : od;
  float4 f = ((const float4*)in)[i];
  f16x4 o; o[0] = (f16)f.x; o[1] = (f16)f.y; o[2] = (f16)f.z; o[3] = (f16)f.w;
  ((f16x4*)out)[i] = o;
}

// ---------- LDS-tiled transpose-cast: in[R][C] fp32 -> out[C][R] fp16 ----------
__device__ __forceinline__ void transpose_body(const float* __restrict__ in,
                                               f16* __restrict__ out, int R, int C) {
  const int r0 = blockIdx.y * 64, c0 = blockIdx.x * 64;
  __shared__ float tile[64][65];
  const int t = threadIdx.x;
  const int cc = t & 63, rr = t >> 6;
#pragma unroll
  for (int p = 0; p < 16; p++) {
    int r = p * 4 + rr;
    tile[r][cc] = in[(size_t)(r0 + r) * C + c0 + cc];
  }
  __syncthreads();
#pragma unroll
  for (int p = 0; p < 16; p++) {
    int c = p * 4 + rr;
    out[(size_t)(c0 + c) * R + r0 + cc] = (f16)tile[cc][c];
  }
}

// z=0: Wlk [2048][1024]->[1024][2048] ; z=1: Wlv same ; z=2: Wout [2048][2048] transposed
__global__ __launch_bounds__(256) void transpose3(const float* __restrict__ Wlk,
                                                  const float* __restrict__ Wlv,
                                                  const float* __restrict__ Wout,
                                                  f16* __restrict__ Wlkt,
                                                  f16* __restrict__ Wlvt,
                                                  f16* __restrict__ WoutT) {
  const int z = blockIdx.z;
  if (z < 2 && blockIdx.x >= 16) return;
  if (z == 0) transpose_body(Wlk, Wlkt, 2048, 1024);
  else if (z == 1) transpose_body(Wlv, Wlvt, 2048, 1024);
  else transpose_body(Wout, WoutT, 2048, 2048);
}

__global__ void fold_bq(const float* __restrict__ bq, const float* __restrict__ Wkr,
                        float* __restrict__ bql) {
  int hl = blockIdx.x * 256 + threadIdx.x;
  if (hl >= kHL) return;
  int h = hl >> 6, l = hl & 63;
  float s = 0.f;
  for (int c = 0; c < 128; c++) s += bq[h * 128 + c] * Wkr[l * 128 + c];
  bql[hl] = s;
}

// ---------- direct per-head fold GEMMs (no block-diagonal waste) ----------
// grid (16 d-tiles, 16 heads, 2). K=128 fully staged.
// z=0: Wqlt[h*64+l][d]  = sum_c Wkr[l][c] * Wq16 [d][h*128+c]   (tile 64 x 128)
// z=1: W2t [d][h*64+l]  = sum_c Wvr[l][c] * WoutT[d][h*128+c]   (tile 128 x 64)
__global__ __launch_bounds__(256) void fold2(const float* __restrict__ Wkr,
                                             const float* __restrict__ Wvr,
                                             const f16* __restrict__ Wq16,
                                             const f16* __restrict__ WoutT,
                                             f16* __restrict__ Wqlt,
                                             f16* __restrict__ W2t) {
  __shared__ f16 sA[64 * 136];   // small matrix (Wkr/Wvr) f16, padded stride kills conflicts
  __shared__ f16 sB[128 * 128];  // 128-row slice of Wq16/WoutT (load_lds16: no padding)
  const int z = blockIdx.z;
  const int h = blockIdx.y;
  const int d0 = blockIdx.x * 128;
  const float* Wsm = z ? Wvr : Wkr;
  const f16* Bsrc = (z ? WoutT : Wq16) + h * 128;
  const int tid = threadIdx.x;
  const int w = tid >> 6, lane = tid & 63;
  const int quad = lane >> 4, l16 = lane & 15;

  // stage small fp32 [64][128] -> sA f16 (stride 136)
#pragma unroll
  for (int it = 0; it < 8; it++) {
    int i = it * 256 + tid;            // float4 index over 2048
    float4 f = ((const float4*)Wsm)[i];
    int e = i * 4, r = e >> 7, c = e & 127;
    f16x4 o; o[0] = (f16)f.x; o[1] = (f16)f.y; o[2] = (f16)f.z; o[3] = (f16)f.w;
    *(f16x4*)&sA[r * 136 + c] = o;
  }
  // stage sB rows d0..d0+127, cols h*128..h*128+127 (4 rows per wave-instruction)
#pragma unroll
  for (int c = 0; c < 8; c++) {
    int rbase = w * 32 + c * 4;
    load_lds16(Bsrc + (size_t)(d0 + rbase + (lane >> 4)) * 2048 + (lane & 15) * 8,
               &sB[rbase * 128]);
  }
  __syncthreads();

  if (z == 0) {
    f32x4 acc[4][2];
    for (int mt = 0; mt < 4; mt++)
      for (int nt = 0; nt < 2; nt++) acc[mt][nt] = (f32x4){0.f, 0.f, 0.f, 0.f};
#pragma unroll
    for (int ks = 0; ks < 4; ks++) {
      f16x8 af[4], bf[2];
#pragma unroll
      for (int mt = 0; mt < 4; mt++)
        af[mt] = *(const f16x8*)&sA[(mt * 16 + l16) * 136 + ks * 32 + quad * 8];
#pragma unroll
      for (int nt = 0; nt < 2; nt++)
        bf[nt] = *(const f16x8*)&sB[(w * 32 + nt * 16 + l16) * 128 + ks * 32 + quad * 8];
#pragma unroll
      for (int mt = 0; mt < 4; mt++)
#pragma unroll
        for (int nt = 0; nt < 2; nt++) acc[mt][nt] = mfma16(af[mt], bf[nt], acc[mt][nt]);
    }
#pragma unroll
    for (int mt = 0; mt < 4; mt++)
#pragma unroll
      for (int nt = 0; nt < 2; nt++)
#pragma unroll
        for (int r = 0; r < 4; r++) {
          int row = mt * 16 + quad * 4 + r;                 // l
          int col = d0 + w * 32 + nt * 16 + l16;            // d
          Wqlt[(size_t)(h * 64 + row) * 2048 + col] = (f16)acc[mt][nt][r];
        }
  } else {
    f32x4 acc[2][4];
    for (int mt = 0; mt < 2; mt++)
      for (int nt = 0; nt < 4; nt++) acc[mt][nt] = (f32x4){0.f, 0.f, 0.f, 0.f};
#pragma unroll
    for (int ks = 0; ks < 4; ks++) {
      f16x8 af[2], bf[4];
#pragma unroll
      for (int mt = 0; mt < 2; mt++)
        af[mt] = *(const f16x8*)&sB[(w * 32 + mt * 16 + l16) * 128 + ks * 32 + quad * 8];
#pragma unroll
      for (int nt = 0; nt < 4; nt++)
        bf[nt] = *(const f16x8*)&sA[(nt * 16 + l16) * 136 + ks * 32 + quad * 8];
#pragma unroll
      for (int mt = 0; mt < 2; mt++)
#pragma unroll
        for (int nt = 0; nt < 4; nt++) acc[mt][nt] = mfma16(af[mt], bf[nt], acc[mt][nt]);
    }
#pragma unroll
    for (int mt = 0; mt < 2; mt++)
#pragma unroll
      for (int nt = 0; nt < 4; nt++)
#pragma unroll
        for (int r = 0; r < 4; r++) {
          int row = d0 + w * 32 + mt * 16 + quad * 4 + r;   // d
          int col = nt * 16 + l16;                          // l
          W2t[(size_t)row * 1024 + h * 64 + col] = (f16)acc[mt][nt][r];
        }
  }
}

// ---------- MFMA GEMM: C[M,N] = A[M,K] @ Bt[N,K]^T (+ bias) ----------
template <typename OutT, bool HAS_BIAS>
__device__ __forceinline__ void gemm_body(const f16* __restrict__ A, const f16* __restrict__ Bt,
                                          const float* __restrict__ bias, OutT* __restrict__ C,
                                          int N, int K) {
  __shared__ f16 sA[128 * 64];
  __shared__ f16 sB[128 * 64];
  const int tid = threadIdx.x;
  const int w = tid >> 6, lane = tid & 63;
  const int quad = lane >> 4, l16 = lane & 15;
  const int wm = w >> 1, wn = w & 1;
  const int m0 = blockIdx.y * 128, n0 = blockIdx.x * 128;
  const int rowA = lane >> 3, colA = (lane & 7) * 8;

  f32x4 acc[4][4];
  for (int i = 0; i < 4; i++)
    for (int j = 0; j < 4; j++) acc[i][j] = (f32x4){0.f, 0.f, 0.f, 0.f};

  for (int k0 = 0; k0 < K; k0 += 64) {
    __syncthreads();
#pragma unroll
    for (int c = 0; c < 4; c++) {
      int rl = w * 32 + c * 8;
      load_lds16(A + (size_t)(m0 + rl + rowA) * K + k0 + colA, &sA[rl * 64]);
      load_lds16(Bt + (size_t)(n0 + rl + rowA) * K + k0 + colA, &sB[rl * 64]);
    }
    __syncthreads();
#pragma unroll
    for (int ks = 0; ks < 2; ks++) {
      f16x8 af[4], bfr[4];
#pragma unroll
      for (int mt = 0; mt < 4; mt++)
        af[mt] = *(const f16x8*)&sA[(wm * 64 + mt * 16 + l16) * 64 + ks * 32 + quad * 8];
#pragma unroll
      for (int nt = 0; nt < 4; nt++)
        bfr[nt] = *(const f16x8*)&sB[(wn * 64 + nt * 16 + l16) * 64 + ks * 32 + quad * 8];
#pragma unroll
      for (int mt = 0; mt < 4; mt++) {
#pragma unroll
        for (int nt = 0; nt < 4; nt++)
          acc[mt][nt] = mfma16(af[mt], bfr[nt], acc[mt][nt]);
      }
    }
  }
#pragma unroll
  for (int mt = 0; mt < 4; mt++) {
#pragma unroll
    for (int nt = 0; nt < 4; nt++) {
      int col = n0 + wn * 64 + nt * 16 + l16;
      float bv = HAS_BIAS ? bias[col] : 0.f;
#pragma unroll
      for (int r = 0; r < 4; r++) {
        int row = m0 + wm * 64 + mt * 16 + quad * 4 + r;
        C[(size_t)row * N + col] = (OutT)(acc[mt][nt][r] + bv);
      }
    }
  }
}

__global__ __launch_bounds__(256) void gemm3_f16(
    const f16* __restrict__ A0, const f16* __restrict__ A1, const f16* __restrict__ A2,
    const f16* __restrict__ B0, const f16* __restrict__ B1, const f16* __restrict__ B2,
    const float* __restrict__ c0, const float* __restrict__ c1, const float* __restrict__ c2,
    f16* __restrict__ C0, f16* __restrict__ C1, f16* __restrict__ C2, int N, int K) {
  const f16* A = blockIdx.z == 0 ? A0 : blockIdx.z == 1 ? A1 : A2;
  const f16* Bt = blockIdx.z == 0 ? B0 : blockIdx.z == 1 ? B1 : B2;
  const float* bias = blockIdx.z == 0 ? c0 : blockIdx.z == 1 ? c1 : c2;
  f16* C = blockIdx.z == 0 ? C0 : blockIdx.z == 1 ? C1 : C2;
  gemm_body<f16, true>(A, Bt, bias, C, N, K);
}

__global__ __launch_bounds__(256) void gemm_f32(const f16* __restrict__ A,
                                                const f16* __restrict__ Bt,
                                                const float* __restrict__ bias,
                                                float* __restrict__ C, int N, int K) {
  gemm_body<float, true>(A, Bt, bias, C, N, K);
}

// ---------- LDS-tiled transpose: LV[(b,s)][(h,l)] -> LVt[(b,h)][l][s] ----------
__global__ __launch_bounds__(256) void transpose_lv(const f16* __restrict__ LV,
                                                    f16* __restrict__ LVt) {
  const int bh = blockIdx.y, b = bh >> 4, h = bh & 15;
  const int s0 = blockIdx.x * 64;
  __shared__ f16 tile[64][65];
  const int t = threadIdx.x;
  const int c0 = t & 63, r0 = t >> 6;
#pragma unroll
  for (int r = 0; r < 16; r++) {
    int s = r * 4 + r0;
    tile[s][c0] = LV[(size_t)(b * kS + s0 + s) * kHL + h * kL + c0];
  }
  __syncthreads();
#pragma unroll
  for (int r = 0; r < 16; r++) {
    int vl = r * 4 + r0;
    LVt[((size_t)bh * kL + vl) * kS + s0 + c0] = tile[c0][vl];
  }
}

// ---------- latent flash attention (load-balanced causal) ----------
// 64-row q-tiles; block processes complementary tiles (p, 31-p) => every block
// does exactly 33 kv-iterations. 512 blocks = 2/CU for wave-level overlap.
__global__ __launch_bounds__(256) void attn(const f16* __restrict__ Qlat,
                                            const f16* __restrict__ LK,
                                            const f16* __restrict__ LVt,
                                            f16* __restrict__ Ctx) {
  const int bh = blockIdx.y, b = bh >> 4, h = bh & 15;
  const int pair = blockIdx.x;  // 0..15
  const int tid = threadIdx.x;
  const int w = tid >> 6, lane = tid & 63;
  const int quad = lane >> 4, l16 = lane & 15;

  __shared__ f16 sK[64 * 64];     // [kv][l]
  __shared__ f16 sV[64 * 64];     // [vl][kv]
  __shared__ f16 sP[4][16 * 72];  // per-wave P tile [q][kv], stride 72 kills bank conflicts

  const f16* qbase = Qlat + (size_t)b * kS * kHL + h * kL;
  const f16* kbase = LK + (size_t)b * kS * kHL + h * kL;
  const f16* vbase = LVt + (size_t)bh * kL * kS;

  const float scale = 0.08838834764831845f;  // 1/sqrt(128)
  const int rowA = lane >> 3, colA = (lane & 7) * 8;

#pragma unroll
  for (int which = 0; which < 2; which++) {
    const int t = which ? (31 - pair) : pair;
    const int q0 = t * 64;
    const int qrow = q0 + w * 16 + l16;

    f16x8 aq[2];
#pragma unroll
    for (int ks = 0; ks < 2; ks++)
      aq[ks] = *(const f16x8*)(qbase + (size_t)qrow * kHL + ks * 32 + quad * 8);

    f32x4 acc[4];
    for (int nt = 0; nt < 4; nt++) acc[nt] = (f32x4){0.f, 0.f, 0.f, 0.f};
    float mst[4], lst[4];
    for (int r = 0; r < 4; r++) { mst[r] = -3.0e38f; lst[r] = 0.f; }

    for (int kv0 = 0; kv0 <= q0; kv0 += 64) {
      __syncthreads();
#pragma unroll
      for (int c = 0; c < 2; c++) {
        int rl = w * 16 + c * 8;
        load_lds16(kbase + (size_t)(kv0 + rl + rowA) * kHL + colA, &sK[rl * 64]);
        load_lds16(vbase + (size_t)(rl + rowA) * kS + kv0 + colA, &sV[rl * 64]);
      }
      __syncthreads();

      f32x4 sc[4];
      for (int nt = 0; nt < 4; nt++) sc[nt] = (f32x4){0.f, 0.f, 0.f, 0.f};
#pragma unroll
      for (int ks = 0; ks < 2; ks++) {
        f16x8 bk[4];
#pragma unroll
        for (int nt = 0; nt < 4; nt++)
          bk[nt] = *(const f16x8*)&sK[(nt * 16 + l16) * 64 + ks * 32 + quad * 8];
#pragma unroll
        for (int nt = 0; nt < 4; nt++) sc[nt] = mfma16(aq[ks], bk[nt], sc[nt]);
      }

      float tmax[4] = {-3.0e38f, -3.0e38f, -3.0e38f, -3.0e38f};
      if (kv0 == q0) {  // diagonal tile: causal mask
#pragma unroll
        for (int nt = 0; nt < 4; nt++) {
          int kvg = kv0 + nt * 16 + l16;
#pragma unroll
          for (int r = 0; r < 4; r++) {
            int qg = q0 + w * 16 + quad * 4 + r;
            float s = sc[nt][r] * scale;
            if (kvg > qg) s = -1.0e30f;
            sc[nt][r] = s;
            tmax[r] = fmaxf(tmax[r], s);
          }
        }
      } else {
#pragma unroll
        for (int nt = 0; nt < 4; nt++) {
#pragma unroll
          for (int r = 0; r < 4; r++) {
            float s = sc[nt][r] * scale;
            sc[nt][r] = s;
            tmax[r] = fmaxf(tmax[r], s);
          }
        }
      }
#pragma unroll
      for (int r = 0; r < 4; r++) {
        float tm = tmax[r];
        tm = fmaxf(tm, __shfl_xor(tm, 1));
        tm = fmaxf(tm, __shfl_xor(tm, 2));
        tm = fmaxf(tm, __shfl_xor(tm, 4));
        tm = fmaxf(tm, __shfl_xor(tm, 8));
        tmax[r] = tm;
      }
      float alpha[4], psum[4];
#pragma unroll
      for (int r = 0; r < 4; r++) {
        float mnew = fmaxf(mst[r], tmax[r]);
        alpha[r] = __expf(mst[r] - mnew);
        mst[r] = mnew;
        psum[r] = 0.f;
      }
#pragma unroll
      for (int nt = 0; nt < 4; nt++) {
#pragma unroll
        for (int r = 0; r < 4; r++) {
          float p = __expf(sc[nt][r] - mst[r]);
          psum[r] += p;
          sP[w][(quad * 4 + r) * 72 + nt * 16 + l16] = (f16)p;
        }
      }
#pragma unroll
      for (int r = 0; r < 4; r++) {
        float s = psum[r];
        s += __shfl_xor(s, 1);
        s += __shfl_xor(s, 2);
        s += __shfl_xor(s, 4);
        s += __shfl_xor(s, 8);
        lst[r] = lst[r] * alpha[r] + s;
      }
#pragma unroll
      for (int nt = 0; nt < 4; nt++) {
#pragma unroll
        for (int r = 0; r < 4; r++) acc[nt][r] *= alpha[r];
      }

#pragma unroll
      for (int ks = 0; ks < 2; ks++) {
        f16x8 ap = *(const f16x8*)&sP[w][l16 * 72 + ks * 32 + quad * 8];
        f16x8 bv[4];
#pragma unroll
        for (int nt = 0; nt < 4; nt++)
          bv[nt] = *(const f16x8*)&sV[(nt * 16 + l16) * 64 + ks * 32 + quad * 8];
#pragma unroll
        for (int nt = 0; nt < 4; nt++) acc[nt] = mfma16(ap, bv[nt], acc[nt]);
      }
    }

#pragma unroll
    for (int r = 0; r < 4; r++) {
      float inv = 1.f / lst[r];
      int qg = q0 + w * 16 + quad * 4 + r;
      size_t base = (size_t)(b * kS + qg) * kHL + h * kL;
#pragma unroll
      for (int nt = 0; nt < 4; nt++)
        Ctx[base + nt * 16 + l16] = (f16)(acc[nt][r] * inv);
    }
  }
}

extern "C" void kernel_launch(void* const* d_in, const int* in_sizes, int n_in,
                              void* d_out, int out_size, void* d_ws, size_t ws_size,
                              hipStream_t stream) {
  (void)in_sizes; (void)n_in; (void)out_size; (void)ws_size;
  const float* queries = (const float*)d_in[0];
  const float* keys    = (const float*)d_in[1];
  const float* values  = (const float*)d_in[2];
  const float* Wq      = (const float*)d_in[3];
  const float* bq      = (const float*)d_in[4];
  const float* Wlk     = (const float*)d_in[5];
  const float* blk     = (const float*)d_in[6];
  const float* Wlv     = (const float*)d_in[7];
  const float* blv     = (const float*)d_in[8];
  const float* Wkr     = (const float*)d_in[9];
  const float* Wvr     = (const float*)d_in[10];
  const float* Wout    = (const float*)d_in[11];
  const float* bout    = (const float*)d_in[12];

  char* ws = (char*)d_ws;
  size_t off = 0;
  auto alloc = [&](size_t bytes) {
    void* p = ws + off;
    off += (bytes + 255) & ~(size_t)255;
    return p;
  };
  f16* qb    = (f16*)alloc((size_t)kBS * kD * 2);
  f16* kb    = (f16*)alloc((size_t)kBS * kD * 2);
  f16* vb    = (f16*)alloc((size_t)kBS * kD * 2);
  f16* Wqlt  = (f16*)alloc((size_t)kHL * kD * 2);
  f16* Wlkt  = (f16*)alloc((size_t)kHL * kD * 2);
  f16* Wlvt  = (f16*)alloc((size_t)kHL * kD * 2);
  f16* W2t   = (f16*)alloc((size_t)kD * kHL * 2);
  float* bql = (float*)alloc(kHL * 4);
  f16* Qlat  = (f16*)alloc((size_t)kBS * kHL * 2);
  f16* LKb   = (f16*)alloc((size_t)kBS * kHL * 2);
  f16* LVb   = (f16*)alloc((size_t)kBS * kHL * 2);
  // prep-only buffers alias post-fold intermediates (dead by the time those are written):
  f16* Wq16  = Qlat;   // 8 MB (kD*kD f16), consumed by fold2 before gemm3 writes Qlat
  f16* WoutT = LKb;    // 8 MB, consumed by fold2 before gemm3 writes LKb
  // input-cast buffers alias post-attn intermediates:
  f16* LVtb = qb;  // LV transposed [b,h][l][s] — qb dead after gemm3
  f16* Ctx  = kb;  // attention output — kb dead after gemm3

  const int n4 = kBS * kD / 4;  // 2M float4 per q/k/v tensor
  cast4<<<dim3(n4 / 256, 1, 4), 256, 0, stream>>>(queries, keys, values, Wq, qb, kb, vb, Wq16);
  transpose3<<<dim3(32, 32, 3), 256, 0, stream>>>(Wlk, Wlv, Wout, Wlkt, Wlvt, WoutT);
  fold_bq<<<kHL / 256, 256, 0, stream>>>(bq, Wkr, bql);
  fold2<<<dim3(16, 16, 2), 256, 0, stream>>>(Wkr, Wvr, Wq16, WoutT, Wqlt, W2t);

  gemm3_f16<<<dim3(kHL / 128, kBS / 128, 3), 256, 0, stream>>>(
      qb, kb, vb, Wqlt, Wlkt, Wlvt, bql, blk, blv, Qlat, LKb, LVb, kHL, kD);

  transpose_lv<<<dim3(kS / 64, kB * kH), 256, 0, stream>>>(LVb, LVtb);
  attn<<<dim3(16, kB * kH), 256, 0, stream>>>(Qlat, LKb, LVtb, Ctx);
  gemm_f32<<<dim3(kD / 128, kBS / 128), 256, 0, stream>>>(Ctx, W2t, bout, (float*)d_out, kD, kHL);
}

// Round 6
// 388.143 us; speedup vs baseline: 1.9638x; 1.0795x over previous
//
#include <hip/hip_runtime.h>
#include <cstdint>
#include <cstddef>

typedef _Float16 f16;
typedef __attribute__((ext_vector_type(8))) _Float16 f16x8;
typedef __attribute__((ext_vector_type(4))) _Float16 f16x4;
typedef __attribute__((ext_vector_type(4))) float f32x4;

constexpr int kB  = 2;
constexpr int kS  = 2048;
constexpr int kD  = 2048;
constexpr int kH  = 16;
constexpr int kL  = 64;
constexpr int kHL = kH * kL;   // 1024
constexpr int kBS = kB * kS;   // 4096

__device__ __forceinline__ void load_lds16(const void* g, void* l) {
  __builtin_amdgcn_global_load_lds((const __attribute__((address_space(1))) void*)g,
                                   (__attribute__((address_space(3))) void*)l, 16, 0, 0);
}

__device__ __forceinline__ f32x4 mfma16(f16x8 a, f16x8 b, f32x4 c) {
  return __builtin_amdgcn_mfma_f32_16x16x32_f16(a, b, c, 0, 0, 0);
}

// XOR-swizzle: chunk c (8 f16) of row r lives at LDS chunk (c ^ (r&7)).
// Staging lane i (of a load_lds16 covering 8 rows x 8 chunks) therefore reads
// global chunk ((i&7) ^ (i>>3)) of local row (i>>3); reads XOR with (row&7).
// Spreads every b128 fragment read across all 32 banks (8-phase minimum).

// ---------- merged fp32 -> fp16 cast: z=0..2 q/k/v (8M elems), z=3 Wq (4M elems) ----------
__global__ void cast4(const float* __restrict__ a, const float* __restrict__ b,
                      const float* __restrict__ c, const float* __restrict__ d,
                      f16* __restrict__ oa, f16* __restrict__ ob,
                      f16* __restrict__ oc, f16* __restrict__ od) {
  const int z = blockIdx.z;
  int i = blockIdx.x * 256 + threadIdx.x;
  if (z == 3 && i >= kD * kD / 4) return;
  const float* in = z == 0 ? a : z == 1 ? b : z == 2 ? c : d;
  f16* out = z == 0 ? oa : z == 1 ? ob : z == 2 ? oc : od;
  float4 f = ((const float4*)in)[i];
  f16x4 o; o[0] = (f16)f.x; o[1] = (f16)f.y; o[2] = (f16)f.z; o[3] = (f16)f.w;
  ((f16x4*)out)[i] = o;
}

// ---------- LDS-tiled transpose-cast: in[R][C] fp32 -> out[C][R] fp16 ----------
__device__ __forceinline__ void transpose_body(const float* __restrict__ in,
                                               f16* __restrict__ out, int R, int C) {
  const int r0 = blockIdx.y * 64, c0 = blockIdx.x * 64;
  __shared__ float tile[64][65];
  const int t = threadIdx.x;
  const int cc = t & 63, rr = t >> 6;
#pragma unroll
  for (int p = 0; p < 16; p++) {
    int r = p * 4 + rr;
    tile[r][cc] = in[(size_t)(r0 + r) * C + c0 + cc];
  }
  __syncthreads();
#pragma unroll
  for (int p = 0; p < 16; p++) {
    int c = p * 4 + rr;
    out[(size_t)(c0 + c) * R + r0 + cc] = (f16)tile[cc][c];
  }
}

// z=0: Wlk [2048][1024]->[1024][2048] ; z=1: Wlv same ; z=2: Wout [2048][2048] transposed
__global__ __launch_bounds__(256) void transpose3(const float* __restrict__ Wlk,
                                                  const float* __restrict__ Wlv,
                                                  const float* __restrict__ Wout,
                                                  f16* __restrict__ Wlkt,
                                                  f16* __restrict__ Wlvt,
                                                  f16* __restrict__ WoutT) {
  const int z = blockIdx.z;
  if (z < 2 && blockIdx.x >= 16) return;
  if (z == 0) transpose_body(Wlk, Wlkt, 2048, 1024);
  else if (z == 1) transpose_body(Wlv, Wlvt, 2048, 1024);
  else transpose_body(Wout, WoutT, 2048, 2048);
}

__global__ void fold_bq(const float* __restrict__ bq, const float* __restrict__ Wkr,
                        float* __restrict__ bql) {
  int hl = blockIdx.x * 256 + threadIdx.x;
  if (hl >= kHL) return;
  int h = hl >> 6, l = hl & 63;
  float s = 0.f;
  for (int c = 0; c < 128; c++) s += bq[h * 128 + c] * Wkr[l * 128 + c];
  bql[hl] = s;
}

// ---------- direct per-head fold GEMMs ----------
// z=0: Wqlt[h*64+l][d]  = sum_c Wkr[l][c] * Wq16 [d][h*128+c]   (tile 64 x 128)
// z=1: W2t [d][h*64+l]  = sum_c Wvr[l][c] * WoutT[d][h*128+c]   (tile 128 x 64)
__global__ __launch_bounds__(256) void fold2(const float* __restrict__ Wkr,
                                             const float* __restrict__ Wvr,
                                             const f16* __restrict__ Wq16,
                                             const f16* __restrict__ WoutT,
                                             f16* __restrict__ Wqlt,
                                             f16* __restrict__ W2t) {
  __shared__ f16 sA[64 * 136];
  __shared__ f16 sB[128 * 128];
  const int z = blockIdx.z;
  const int h = blockIdx.y;
  const int d0 = blockIdx.x * 128;
  const float* Wsm = z ? Wvr : Wkr;
  const f16* Bsrc = (z ? WoutT : Wq16) + h * 128;
  const int tid = threadIdx.x;
  const int w = tid >> 6, lane = tid & 63;
  const int quad = lane >> 4, l16 = lane & 15;

#pragma unroll
  for (int it = 0; it < 8; it++) {
    int i = it * 256 + tid;
    float4 f = ((const float4*)Wsm)[i];
    int e = i * 4, r = e >> 7, c = e & 127;
    f16x4 o; o[0] = (f16)f.x; o[1] = (f16)f.y; o[2] = (f16)f.z; o[3] = (f16)f.w;
    *(f16x4*)&sA[r * 136 + c] = o;
  }
#pragma unroll
  for (int c = 0; c < 8; c++) {
    int rbase = w * 32 + c * 4;
    load_lds16(Bsrc + (size_t)(d0 + rbase + (lane >> 4)) * 2048 + (lane & 15) * 8,
               &sB[rbase * 128]);
  }
  __syncthreads();

  if (z == 0) {
    f32x4 acc[4][2];
    for (int mt = 0; mt < 4; mt++)
      for (int nt = 0; nt < 2; nt++) acc[mt][nt] = (f32x4){0.f, 0.f, 0.f, 0.f};
#pragma unroll
    for (int ks = 0; ks < 4; ks++) {
      f16x8 af[4], bf[2];
#pragma unroll
      for (int mt = 0; mt < 4; mt++)
        af[mt] = *(const f16x8*)&sA[(mt * 16 + l16) * 136 + ks * 32 + quad * 8];
#pragma unroll
      for (int nt = 0; nt < 2; nt++)
        bf[nt] = *(const f16x8*)&sB[(w * 32 + nt * 16 + l16) * 128 + ks * 32 + quad * 8];
#pragma unroll
      for (int mt = 0; mt < 4; mt++)
#pragma unroll
        for (int nt = 0; nt < 2; nt++) acc[mt][nt] = mfma16(af[mt], bf[nt], acc[mt][nt]);
    }
#pragma unroll
    for (int mt = 0; mt < 4; mt++)
#pragma unroll
      for (int nt = 0; nt < 2; nt++)
#pragma unroll
        for (int r = 0; r < 4; r++) {
          int row = mt * 16 + quad * 4 + r;
          int col = d0 + w * 32 + nt * 16 + l16;
          Wqlt[(size_t)(h * 64 + row) * 2048 + col] = (f16)acc[mt][nt][r];
        }
  } else {
    f32x4 acc[2][4];
    for (int mt = 0; mt < 2; mt++)
      for (int nt = 0; nt < 4; nt++) acc[mt][nt] = (f32x4){0.f, 0.f, 0.f, 0.f};
#pragma unroll
    for (int ks = 0; ks < 4; ks++) {
      f16x8 af[2], bf[4];
#pragma unroll
      for (int mt = 0; mt < 2; mt++)
        af[mt] = *(const f16x8*)&sB[(w * 32 + mt * 16 + l16) * 128 + ks * 32 + quad * 8];
#pragma unroll
      for (int nt = 0; nt < 4; nt++)
        bf[nt] = *(const f16x8*)&sA[(nt * 16 + l16) * 136 + ks * 32 + quad * 8];
#pragma unroll
      for (int mt = 0; mt < 2; mt++)
#pragma unroll
        for (int nt = 0; nt < 4; nt++) acc[mt][nt] = mfma16(af[mt], bf[nt], acc[mt][nt]);
    }
#pragma unroll
    for (int mt = 0; mt < 2; mt++)
#pragma unroll
      for (int nt = 0; nt < 4; nt++)
#pragma unroll
        for (int r = 0; r < 4; r++) {
          int row = d0 + w * 32 + mt * 16 + quad * 4 + r;
          int col = nt * 16 + l16;
          W2t[(size_t)row * 1024 + h * 64 + col] = (f16)acc[mt][nt][r];
        }
  }
}

// ---------- MFMA GEMM: C[M,N] = A[M,K] @ Bt[N,K]^T (+ bias), swizzled LDS ----------
template <typename OutT, bool HAS_BIAS>
__device__ __forceinline__ void gemm_body(const f16* __restrict__ A, const f16* __restrict__ Bt,
                                          const float* __restrict__ bias, OutT* __restrict__ C,
                                          int N, int K) {
  __shared__ f16 sA[128 * 64];
  __shared__ f16 sB[128 * 64];
  const int tid = threadIdx.x;
  const int w = tid >> 6, lane = tid & 63;
  const int quad = lane >> 4, l16 = lane & 15;
  const int wm = w >> 1, wn = w & 1;
  const int m0 = blockIdx.y * 128, n0 = blockIdx.x * 128;
  const int rowA = lane >> 3;
  const int colSw = (((lane & 7) ^ (lane >> 3)) << 3) ;      // swizzled global chunk
  const int sw0 = ((quad ^ (l16 & 7)) << 3);                 // ks=0 read offset
  const int sw1 = (((4 + quad) ^ (l16 & 7)) << 3);           // ks=1 read offset

  f32x4 acc[4][4];
  for (int i = 0; i < 4; i++)
    for (int j = 0; j < 4; j++) acc[i][j] = (f32x4){0.f, 0.f, 0.f, 0.f};

  for (int k0 = 0; k0 < K; k0 += 64) {
    __syncthreads();
#pragma unroll
    for (int c = 0; c < 4; c++) {
      int rl = w * 32 + c * 8;
      load_lds16(A + (size_t)(m0 + rl + rowA) * K + k0 + colSw, &sA[rl * 64]);
      load_lds16(Bt + (size_t)(n0 + rl + rowA) * K + k0 + colSw, &sB[rl * 64]);
    }
    __syncthreads();
#pragma unroll
    for (int ks = 0; ks < 2; ks++) {
      const int sw = ks ? sw1 : sw0;
      f16x8 af[4], bfr[4];
#pragma unroll
      for (int mt = 0; mt < 4; mt++)
        af[mt] = *(const f16x8*)&sA[(wm * 64 + mt * 16 + l16) * 64 + sw];
#pragma unroll
      for (int nt = 0; nt < 4; nt++)
        bfr[nt] = *(const f16x8*)&sB[(wn * 64 + nt * 16 + l16) * 64 + sw];
#pragma unroll
      for (int mt = 0; mt < 4; mt++) {
#pragma unroll
        for (int nt = 0; nt < 4; nt++)
          acc[mt][nt] = mfma16(af[mt], bfr[nt], acc[mt][nt]);
      }
    }
  }
#pragma unroll
  for (int mt = 0; mt < 4; mt++) {
#pragma unroll
    for (int nt = 0; nt < 4; nt++) {
      int col = n0 + wn * 64 + nt * 16 + l16;
      float bv = HAS_BIAS ? bias[col] : 0.f;
#pragma unroll
      for (int r = 0; r < 4; r++) {
        int row = m0 + wm * 64 + mt * 16 + quad * 4 + r;
        C[(size_t)row * N + col] = (OutT)(acc[mt][nt][r] + bv);
      }
    }
  }
}

__global__ __launch_bounds__(256) void gemm3_f16(
    const f16* __restrict__ A0, const f16* __restrict__ A1, const f16* __restrict__ A2,
    const f16* __restrict__ B0, const f16* __restrict__ B1, const f16* __restrict__ B2,
    const float* __restrict__ c0, const float* __restrict__ c1, const float* __restrict__ c2,
    f16* __restrict__ C0, f16* __restrict__ C1, f16* __restrict__ C2, int N, int K) {
  const f16* A = blockIdx.z == 0 ? A0 : blockIdx.z == 1 ? A1 : A2;
  const f16* Bt = blockIdx.z == 0 ? B0 : blockIdx.z == 1 ? B1 : B2;
  const float* bias = blockIdx.z == 0 ? c0 : blockIdx.z == 1 ? c1 : c2;
  f16* C = blockIdx.z == 0 ? C0 : blockIdx.z == 1 ? C1 : C2;
  gemm_body<f16, true>(A, Bt, bias, C, N, K);
}

__global__ __launch_bounds__(256) void gemm_f32(const f16* __restrict__ A,
                                                const f16* __restrict__ Bt,
                                                const float* __restrict__ bias,
                                                float* __restrict__ C, int N, int K) {
  gemm_body<float, true>(A, Bt, bias, C, N, K);
}

// ---------- LDS-tiled transpose: LV[(b,s)][(h,l)] -> LVt[(b,h)][l][s] ----------
__global__ __launch_bounds__(256) void transpose_lv(const f16* __restrict__ LV,
                                                    f16* __restrict__ LVt) {
  const int bh = blockIdx.y, b = bh >> 4, h = bh & 15;
  const int s0 = blockIdx.x * 64;
  __shared__ f16 tile[64][65];
  const int t = threadIdx.x;
  const int c0 = t & 63, r0 = t >> 6;
#pragma unroll
  for (int r = 0; r < 16; r++) {
    int s = r * 4 + r0;
    tile[s][c0] = LV[(size_t)(b * kS + s0 + s) * kHL + h * kL + c0];
  }
  __syncthreads();
#pragma unroll
  for (int r = 0; r < 16; r++) {
    int vl = r * 4 + r0;
    LVt[((size_t)bh * kL + vl) * kS + s0 + c0] = tile[c0][vl];
  }
}

// ---------- latent flash attention (load-balanced causal, swizzled LDS) ----------
__global__ __launch_bounds__(256) void attn(const f16* __restrict__ Qlat,
                                            const f16* __restrict__ LK,
                                            const f16* __restrict__ LVt,
                                            f16* __restrict__ Ctx) {
  const int bh = blockIdx.y, b = bh >> 4, h = bh & 15;
  const int pair = blockIdx.x;  // 0..15
  const int tid = threadIdx.x;
  const int w = tid >> 6, lane = tid & 63;
  const int quad = lane >> 4, l16 = lane & 15;

  __shared__ f16 sK[64 * 64];     // [kv][l], swizzled chunks
  __shared__ f16 sV[64 * 64];     // [vl][kv], swizzled chunks
  __shared__ f16 sP[4][16 * 72];  // per-wave P tile [q][kv], stride 72

  const f16* qbase = Qlat + (size_t)b * kS * kHL + h * kL;
  const f16* kbase = LK + (size_t)b * kS * kHL + h * kL;
  const f16* vbase = LVt + (size_t)bh * kL * kS;

  const float scale = 0.08838834764831845f;  // 1/sqrt(128)
  const int rowA = lane >> 3;
  const int colSw = (((lane & 7) ^ (lane >> 3)) << 3);
  const int sw0 = ((quad ^ (l16 & 7)) << 3);
  const int sw1 = (((4 + quad) ^ (l16 & 7)) << 3);

#pragma unroll
  for (int which = 0; which < 2; which++) {
    const int t = which ? (31 - pair) : pair;
    const int q0 = t * 64;
    const int qrow = q0 + w * 16 + l16;

    f16x8 aq[2];
#pragma unroll
    for (int ks = 0; ks < 2; ks++)
      aq[ks] = *(const f16x8*)(qbase + (size_t)qrow * kHL + ks * 32 + quad * 8);

    f32x4 acc[4];
    for (int nt = 0; nt < 4; nt++) acc[nt] = (f32x4){0.f, 0.f, 0.f, 0.f};
    float mst[4], lst[4];
    for (int r = 0; r < 4; r++) { mst[r] = -3.0e38f; lst[r] = 0.f; }

    for (int kv0 = 0; kv0 <= q0; kv0 += 64) {
      __syncthreads();
#pragma unroll
      for (int c = 0; c < 2; c++) {
        int rl = w * 16 + c * 8;
        load_lds16(kbase + (size_t)(kv0 + rl + rowA) * kHL + colSw, &sK[rl * 64]);
        load_lds16(vbase + (size_t)(rl + rowA) * kS + kv0 + colSw, &sV[rl * 64]);
      }
      __syncthreads();

      f32x4 sc[4];
      for (int nt = 0; nt < 4; nt++) sc[nt] = (f32x4){0.f, 0.f, 0.f, 0.f};
#pragma unroll
      for (int ks = 0; ks < 2; ks++) {
        const int sw = ks ? sw1 : sw0;
        f16x8 bk[4];
#pragma unroll
        for (int nt = 0; nt < 4; nt++)
          bk[nt] = *(const f16x8*)&sK[(nt * 16 + l16) * 64 + sw];
#pragma unroll
        for (int nt = 0; nt < 4; nt++) sc[nt] = mfma16(aq[ks], bk[nt], sc[nt]);
      }

      float tmax[4] = {-3.0e38f, -3.0e38f, -3.0e38f, -3.0e38f};
      if (kv0 == q0) {  // diagonal tile: causal mask
#pragma unroll
        for (int nt = 0; nt < 4; nt++) {
          int kvg = kv0 + nt * 16 + l16;
#pragma unroll
          for (int r = 0; r < 4; r++) {
            int qg = q0 + w * 16 + quad * 4 + r;
            float s = sc[nt][r] * scale;
            if (kvg > qg) s = -1.0e30f;
            sc[nt][r] = s;
            tmax[r] = fmaxf(tmax[r], s);
          }
        }
      } else {
#pragma unroll
        for (int nt = 0; nt < 4; nt++) {
#pragma unroll
          for (int r = 0; r < 4; r++) {
            float s = sc[nt][r] * scale;
            sc[nt][r] = s;
            tmax[r] = fmaxf(tmax[r], s);
          }
        }
      }
#pragma unroll
      for (int r = 0; r < 4; r++) {
        float tm = tmax[r];
        tm = fmaxf(tm, __shfl_xor(tm, 1));
        tm = fmaxf(tm, __shfl_xor(tm, 2));
        tm = fmaxf(tm, __shfl_xor(tm, 4));
        tm = fmaxf(tm, __shfl_xor(tm, 8));
        tmax[r] = tm;
      }
      float alpha[4], psum[4];
#pragma unroll
      for (int r = 0; r < 4; r++) {
        float mnew = fmaxf(mst[r], tmax[r]);
        alpha[r] = __expf(mst[r] - mnew);
        mst[r] = mnew;
        psum[r] = 0.f;
      }
#pragma unroll
      for (int nt = 0; nt < 4; nt++) {
#pragma unroll
        for (int r = 0; r < 4; r++) {
          float p = __expf(sc[nt][r] - mst[r]);
          psum[r] += p;
          sP[w][(quad * 4 + r) * 72 + nt * 16 + l16] = (f16)p;
        }
      }
#pragma unroll
      for (int r = 0; r < 4; r++) {
        float s = psum[r];
        s += __shfl_xor(s, 1);
        s += __shfl_xor(s, 2);
        s += __shfl_xor(s, 4);
        s += __shfl_xor(s, 8);
        lst[r] = lst[r] * alpha[r] + s;
      }
#pragma unroll
      for (int nt = 0; nt < 4; nt++) {
#pragma unroll
        for (int r = 0; r < 4; r++) acc[nt][r] *= alpha[r];
      }

#pragma unroll
      for (int ks = 0; ks < 2; ks++) {
        const int sw = ks ? sw1 : sw0;
        f16x8 ap = *(const f16x8*)&sP[w][l16 * 72 + ks * 32 + quad * 8];
        f16x8 bv[4];
#pragma unroll
        for (int nt = 0; nt < 4; nt++)
          bv[nt] = *(const f16x8*)&sV[(nt * 16 + l16) * 64 + sw];
#pragma unroll
        for (int nt = 0; nt < 4; nt++) acc[nt] = mfma16(ap, bv[nt], acc[nt]);
      }
    }

#pragma unroll
    for (int r = 0; r < 4; r++) {
      float inv = 1.f / lst[r];
      int qg = q0 + w * 16 + quad * 4 + r;
      size_t base = (size_t)(b * kS + qg) * kHL + h * kL;
#pragma unroll
      for (int nt = 0; nt < 4; nt++)
        Ctx[base + nt * 16 + l16] = (f16)(acc[nt][r] * inv);
    }
  }
}

extern "C" void kernel_launch(void* const* d_in, const int* in_sizes, int n_in,
                              void* d_out, int out_size, void* d_ws, size_t ws_size,
                              hipStream_t stream) {
  (void)in_sizes; (void)n_in; (void)out_size; (void)ws_size;
  const float* queries = (const float*)d_in[0];
  const float* keys    = (const float*)d_in[1];
  const float* values  = (const float*)d_in[2];
  const float* Wq      = (const float*)d_in[3];
  const float* bq      = (const float*)d_in[4];
  const float* Wlk     = (const float*)d_in[5];
  const float* blk     = (const float*)d_in[6];
  const float* Wlv     = (const float*)d_in[7];
  const float* blv     = (const float*)d_in[8];
  const float* Wkr     = (const float*)d_in[9];
  const float* Wvr     = (const float*)d_in[10];
  const float* Wout    = (const float*)d_in[11];
  const float* bout    = (const float*)d_in[12];

  char* ws = (char*)d_ws;
  size_t off = 0;
  auto alloc = [&](size_t bytes) {
    void* p = ws + off;
    off += (bytes + 255) & ~(size_t)255;
    return p;
  };
  f16* qb    = (f16*)alloc((size_t)kBS * kD * 2);
  f16* kb    = (f16*)alloc((size_t)kBS * kD * 2);
  f16* vb    = (f16*)alloc((size_t)kBS * kD * 2);
  f16* Wqlt  = (f16*)alloc((size_t)kHL * kD * 2);
  f16* Wlkt  = (f16*)alloc((size_t)kHL * kD * 2);
  f16* Wlvt  = (f16*)alloc((size_t)kHL * kD * 2);
  f16* W2t   = (f16*)alloc((size_t)kD * kHL * 2);
  float* bql = (float*)alloc(kHL * 4);
  f16* Qlat  = (f16*)alloc((size_t)kBS * kHL * 2);
  f16* LKb   = (f16*)alloc((size_t)kBS * kHL * 2);
  f16* LVb   = (f16*)alloc((size_t)kBS * kHL * 2);
  // prep-only buffers alias post-fold intermediates (dead by the time those are written):
  f16* Wq16  = Qlat;   // 8 MB (kD*kD f16), consumed by fold2 before gemm3 writes Qlat
  f16* WoutT = LKb;    // 8 MB, consumed by fold2 before gemm3 writes LKb
  // input-cast buffers alias post-attn intermediates:
  f16* LVtb = qb;  // LV transposed [b,h][l][s] — qb dead after gemm3
  f16* Ctx  = kb;  // attention output — kb dead after gemm3

  const int n4 = kBS * kD / 4;  // 2M float4 per q/k/v tensor
  cast4<<<dim3(n4 / 256, 1, 4), 256, 0, stream>>>(queries, keys, values, Wq, qb, kb, vb, Wq16);
  transpose3<<<dim3(32, 32, 3), 256, 0, stream>>>(Wlk, Wlv, Wout, Wlkt, Wlvt, WoutT);
  fold_bq<<<kHL / 256, 256, 0, stream>>>(bq, Wkr, bql);
  fold2<<<dim3(16, 16, 2), 256, 0, stream>>>(Wkr, Wvr, Wq16, WoutT, Wqlt, W2t);

  gemm3_f16<<<dim3(kHL / 128, kBS / 128, 3), 256, 0, stream>>>(
      qb, kb, vb, Wqlt, Wlkt, Wlvt, bql, blk, blv, Qlat, LKb, LVb, kHL, kD);

  transpose_lv<<<dim3(kS / 64, kB * kH), 256, 0, stream>>>(LVb, LVtb);
  attn<<<dim3(16, kB * kH), 256, 0, stream>>>(Qlat, LKb, LVtb, Ctx);
  gemm_f32<<<dim3(kD / 128, kBS / 128), 256, 0, stream>>>(Ctx, W2t, bout, (float*)d_out, kD, kHL);
}